// Round 4
// baseline (441.273 us; speedup 1.0000x reference)
//
#include <hip/hip_runtime.h>
#include <hip/hip_bf16.h>
#include <math.h>

// ---------------------------------------------------------------------------
// Mamba2 forward, MI355X. Round 13: keep round-12 GEMMs (BK=64 + XCD swizzle,
// GEMM1 at 89us = m97-structure ceiling). Mid-pipeline basket:
//   - dt_kernel fused into GEMM1 epilogue (softplus on fp32 value, 1 fewer
//     dispatch).
//   - scan_kernel: ushort2 elements (2x waves -> TLP 4/SIMD) + prefetch-2.
//   - chunk_state / y_kernel: serial cumsum -> wave-parallel shfl_up scan.
//   - conv_silu: block 192 (exact 576-thread fit).
// Everything else byte-identical to round 12.
// ---------------------------------------------------------------------------

namespace {

constexpr int kB   = 2;
constexpr int kL   = 4096;
constexpr int kDI  = 2048;
constexpr int kDS  = 128;
constexpr int kNH  = 32;
constexpr int kHP  = 64;
constexpr int kDC  = 4;
constexpr int kCS  = 64;
constexpr int kNC  = kL / kCS;
constexpr int kDProj   = 2 * kDI + 2 * kDS + kNH;  // 4384
constexpr int kDProjP  = 4480;                     // 35*128
constexpr int kConvDim = kDI + 2 * kDS;            // 2304
constexpr int kRows = kB * kL;                     // 8192
constexpr float kEps = 1e-5f;
constexpr int kTS = 136;   // LDS stride for [64][128] tiles
constexpr int kWS = 72;    // LDS stride for [64][64] tiles

typedef __bf16 bf16x8 __attribute__((ext_vector_type(8)));
typedef float f32x4 __attribute__((ext_vector_type(4)));
typedef unsigned short ushort8 __attribute__((ext_vector_type(8)));

__device__ inline float bu2f(unsigned short u) {
  union { unsigned int i; float f; } x; x.i = ((unsigned int)u) << 16; return x.f;
}
__device__ inline unsigned short f2bu(float f) {
  __hip_bfloat16 h = __float2bfloat16(f);
  return *reinterpret_cast<unsigned short*>(&h);
}

__device__ inline void store_out(float* C, size_t i, float v) { C[i] = v; }
__device__ inline void store_out(unsigned short* C, size_t i, float v) { C[i] = f2bu(v); }

__device__ inline void gld_lds16(const unsigned short* g, unsigned short* l) {
  __builtin_amdgcn_global_load_lds(
      (const __attribute__((address_space(1))) unsigned int*)g,
      (__attribute__((address_space(3))) unsigned int*)l, 16, 0, 0);
}

// ---- C0: cast fp32 -> bf16
__global__ void cast_kernel(const float4* __restrict__ in, ushort4* __restrict__ out, int n4) {
  int i = blockIdx.x * 256 + threadIdx.x;
  if (i >= n4) return;
  float4 v = in[i];
  ushort4 o;
  o.x = f2bu(v.x); o.y = f2bu(v.y); o.z = f2bu(v.z); o.w = f2bu(v.w);
  out[i] = o;
}

// ---- C1/C2: transpose + cast (+optional per-row scale)
__global__ void transpose_cast(const float* __restrict__ in, unsigned short* __restrict__ out,
                               int R, int C, const float* __restrict__ scale) {
  __shared__ float t[32][33];
  const int c0 = blockIdx.x * 32;
  const int r0 = blockIdx.y * 32;
  const int tx = threadIdx.x & 31, ty = threadIdx.x >> 5;
  for (int rr = ty; rr < 32; rr += 8) {
    int c = c0 + tx;
    float v = (c < C) ? in[(size_t)(r0 + rr) * C + c] : 0.f;
    if (scale) v *= scale[r0 + rr];
    t[rr][tx] = v;
  }
  __syncthreads();
  for (int cc = ty; cc < 32; cc += 8) {
    int orow = c0 + cc;
    out[(size_t)orow * R + r0 + tx] = f2bu(t[tx][cc]);
  }
}

// ---- C3: t1[n] = sum_k w[k]*W2[k][n], t2[n] = sum_k b[k]*W2[k][n]
__global__ void colsum_kernel(const float* __restrict__ W2, const float* __restrict__ wv,
                              const float* __restrict__ bv,
                              float* __restrict__ t1, float* __restrict__ t2) {
  __shared__ float p1[4][64], p2[4][64];
  const int nl = threadIdx.x & 63;
  const int ks = threadIdx.x >> 6;
  const int n = blockIdx.x * 64 + nl;
  float s1 = 0.f, s2 = 0.f;
  for (int k = ks * 512; k < ks * 512 + 512; k++) {
    float v = W2[(size_t)k * 1024 + n];
    s1 += wv[k] * v;
    s2 += bv[k] * v;
  }
  p1[ks][nl] = s1; p2[ks][nl] = s2;
  __syncthreads();
  if (threadIdx.x < 64) {
    t1[blockIdx.x * 64 + threadIdx.x] =
        p1[0][threadIdx.x] + p1[1][threadIdx.x] + p1[2][threadIdx.x] + p1[3][threadIdx.x];
    t2[blockIdx.x * 64 + threadIdx.x] =
        p2[0][threadIdx.x] + p2[1][threadIdx.x] + p2[2][threadIdx.x] + p2[3][threadIdx.x];
  }
}

// ---- MFMA GEMM, 128x128 tile, BK=64, XOR-swizzled LDS, XCD-swizzled grid.
// FOLD applies LayerNorm in epilogue. Non-FOLD (GEMM1) fuses the dt softplus:
// for n in [kDProj-kNH, kDProj) also writes dtb[m*kNH + h] from the fp32 acc.
template <typename OutT, bool FOLD>
__global__ __launch_bounds__(256, 3) void gemm_bt(const unsigned short* __restrict__ A,
                                                  const unsigned short* __restrict__ Bt,
                                                  OutT* __restrict__ C, int M, int N, int K,
                                                  const float* __restrict__ mu,
                                                  const float* __restrict__ rstd,
                                                  const float* __restrict__ t1,
                                                  const float* __restrict__ t2,
                                                  const float* __restrict__ dt_bias,
                                                  float* __restrict__ dtb) {
  __shared__ __align__(16) unsigned short As[128 * 64];   // 16 KB
  __shared__ __align__(16) unsigned short Bs[128 * 64];   // 16 KB
  const int tid = threadIdx.x;
  const int wave = tid >> 6, lane = tid & 63;
  // T1: bijective XCD swizzle (both grids are multiples of 8)
  const int nwg = (int)(gridDim.x * gridDim.y);
  const int orig = (int)(blockIdx.y * gridDim.x + blockIdx.x);
  const int swz = (orig & 7) * (nwg >> 3) + (orig >> 3);
  const int bx = swz % (int)gridDim.x, by = swz / (int)gridDim.x;
  const int m0 = by * 128, n0 = bx * 128;
  const int wr = (wave >> 1) * 64, wc = (wave & 1) * 64;
  // staging: LDS[row][s] holds global[row][s ^ (row&7)] (dest linear, source
  // pre-swizzled; read slot ^ (row&7)).
  const int l8 = lane >> 3, s8 = lane & 7;
  const unsigned short* pA[4];
  const unsigned short* pB[4];
  unsigned short* lA[4];
  unsigned short* lB[4];
#pragma unroll
  for (int r = 0; r < 4; r++) {
    int q = wave * 4 + r;                       // 16 segments x 8 rows = 128 rows
    pA[r] = A + (size_t)(m0 + q * 8 + l8) * K + (s8 ^ l8) * 8;
    pB[r] = Bt + (size_t)(n0 + q * 8 + l8) * K + (s8 ^ l8) * 8;
    lA[r] = &As[q * 512];
    lB[r] = &Bs[q * 512];
  }
  const int fr = lane & 15;
  const int c4 = lane >> 4;
  const int sk0 = (c4 ^ (fr & 7)) * 8;          // kk=0: slots 0..3, swizzled
  const int sk1 = ((4 | c4) ^ (fr & 7)) * 8;    // kk=1: slots 4..7, swizzled
  f32x4 acc[4][4] = {};
  for (int k0 = 0; k0 < K; k0 += 64) {
#pragma unroll
    for (int r = 0; r < 4; r++) {
      gld_lds16(pA[r] + k0, lA[r]);
      gld_lds16(pB[r] + k0, lB[r]);
    }
    asm volatile("s_waitcnt vmcnt(0)" ::: "memory");
    __syncthreads();
    {
      bf16x8 af0[4], bf0[4];
#pragma unroll
      for (int i = 0; i < 4; i++) {
        af0[i] = *(const bf16x8*)&As[(wr + i * 16 + fr) * 64 + sk0];
        bf0[i] = *(const bf16x8*)&Bs[(wc + i * 16 + fr) * 64 + sk0];
      }
#pragma unroll
      for (int i = 0; i < 4; i++)
#pragma unroll
        for (int j = 0; j < 4; j++)
          acc[i][j] = __builtin_amdgcn_mfma_f32_16x16x32_bf16(af0[i], bf0[j], acc[i][j], 0, 0, 0);
    }
    {
      bf16x8 af1[4], bf1[4];
#pragma unroll
      for (int i = 0; i < 4; i++) {
        af1[i] = *(const bf16x8*)&As[(wr + i * 16 + fr) * 64 + sk1];
        bf1[i] = *(const bf16x8*)&Bs[(wc + i * 16 + fr) * 64 + sk1];
      }
#pragma unroll
      for (int i = 0; i < 4; i++)
#pragma unroll
        for (int j = 0; j < 4; j++)
          acc[i][j] = __builtin_amdgcn_mfma_f32_16x16x32_bf16(af1[i], bf1[j], acc[i][j], 0, 0, 0);
    }
    __syncthreads();
  }
  const int crow = (lane >> 4) * 4;
  const int ccol = lane & 15;
#pragma unroll
  for (int i = 0; i < 4; i++) {
#pragma unroll
    for (int j = 0; j < 4; j++) {
      int n = n0 + wc + j * 16 + ccol;
      if (n < N) {
        float c1 = FOLD ? t1[n] : 0.f;
        float c2 = FOLD ? t2[n] : 0.f;
#pragma unroll
        for (int r = 0; r < 4; r++) {
          int m = m0 + wr + i * 16 + crow + r;
          float v = acc[i][j][r];
          if (FOLD) v = rstd[m] * (v - mu[m] * c1) + c2;
          store_out(C, (size_t)m * N + n, v);
          if (!FOLD && n >= kDProj - kNH) {     // fused dt softplus (GEMM1 only)
            int hh = n - (kDProj - kNH);
            float x = v + dt_bias[hh];
            dtb[(size_t)m * kNH + hh] = (x > 15.f) ? x : log1pf(expf(x));
          }
        }
      }
    }
  }
}

// ---- K3: causal depthwise conv (k=4) + SiLU, 8 rows x 4 cols per thread
__global__ void conv_silu_kernel(const unsigned short* __restrict__ zxbcdt,
                                 const float* __restrict__ conv_w,
                                 const float* __restrict__ conv_b,
                                 unsigned short* __restrict__ xbc_act) {
  int c4 = blockIdx.x * 192 + threadIdx.x;
  if (c4 >= kConvDim / 4) return;
  const int c = c4 * 4;
  const int r0 = blockIdx.y * 8;
  const int l0 = r0 & (kL - 1);
  float4 w[4];
  float bias[4];
#pragma unroll
  for (int q = 0; q < 4; q++) {
    w[q] = ((const float4*)conv_w)[c + q];
    bias[q] = conv_b[c + q];
  }
  float v[11][4];
#pragma unroll
  for (int i = 0; i < 11; i++) {
    int l = l0 - 3 + i;
    if (l >= 0) {
      ushort4 t = *(const ushort4*)&zxbcdt[(size_t)(r0 - 3 + i) * kDProj + kDI + c];
      v[i][0] = bu2f(t.x); v[i][1] = bu2f(t.y); v[i][2] = bu2f(t.z); v[i][3] = bu2f(t.w);
    } else {
      v[i][0] = v[i][1] = v[i][2] = v[i][3] = 0.f;
    }
  }
#pragma unroll
  for (int j = 0; j < 8; j++) {
    ushort4 o;
    unsigned short* op = (unsigned short*)&o;
#pragma unroll
    for (int q = 0; q < 4; q++) {
      float a = bias[q] + v[j][q] * w[q].x + v[j + 1][q] * w[q].y +
                v[j + 2][q] * w[q].z + v[j + 3][q] * w[q].w;
      op[q] = f2bu(a / (1.f + expf(-a)));
    }
    *(ushort4*)&xbc_act[(size_t)(r0 + j) * kConvDim + c] = o;
  }
}

// ---- K4: per-(b,chunk,head) end-of-chunk state via MFMA
__global__ __launch_bounds__(256) void chunk_state_kernel(
    const unsigned short* __restrict__ xbc_act,
    const float* __restrict__ dtbuf,
    const float* __restrict__ A_log,
    unsigned short* __restrict__ states,
    float* __restrict__ asum) {
  const int id = blockIdx.x;
  const int h = id & 31;
  const int c = (id >> 5) & (kNC - 1);
  const int b = id >> 11;
  const int tid = threadIdx.x;
  const int wave = tid >> 6, lane = tid & 63;
  __shared__ __align__(16) unsigned short sBT[kDS * kWS];
  __shared__ __align__(16) unsigned short sxd[kCS * kWS];
  __shared__ float s_dt[kCS];
  __shared__ float s_acum[kCS];
  const int l0 = b * kL + c * kCS;
  if (tid < kCS) s_dt[tid] = dtbuf[(size_t)(l0 + tid) * kNH + h];
  __syncthreads();
  if (tid < 64) {                      // wave-parallel inclusive scan
    float A = -expf(A_log[h]);
    float v = A * s_dt[tid];
#pragma unroll
    for (int off = 1; off < 64; off <<= 1) {
      float u = __shfl_up(v, off);
      if (tid >= off) v += u;
    }
    s_acum[tid] = v;
    if (tid == 63) asum[id] = v;
  }
  __syncthreads();
  const float total = s_acum[kCS - 1];
  for (int e = tid; e < kCS * kDS; e += 256) {
    int s = e >> 7, n = e & 127;
    sBT[n * kWS + s] = xbc_act[(size_t)(l0 + s) * kConvDim + kDI + n];
  }
  for (int e = tid; e < kCS * kHP; e += 256) {
    int s = e >> 6, p = e & 63;
    float xv = bu2f(xbc_act[(size_t)(l0 + s) * kConvDim + h * kHP + p]);
    sxd[p * kWS + s] = f2bu(xv * s_dt[s] * expf(total - s_acum[s]));
  }
  __syncthreads();
  const int arow = wave * 16 + (lane & 15);
  const int fk = (lane >> 4) * 8;
  f32x4 acc[8] = {};
#pragma unroll
  for (int kk = 0; kk < 2; kk++) {
    bf16x8 a = *(const bf16x8*)&sxd[arow * kWS + kk * 32 + fk];
#pragma unroll
    for (int j = 0; j < 8; j++) {
      bf16x8 bb = *(const bf16x8*)&sBT[(j * 16 + (lane & 15)) * kWS + kk * 32 + fk];
      acc[j] = __builtin_amdgcn_mfma_f32_16x16x32_bf16(a, bb, acc[j], 0, 0, 0);
    }
  }
  const int prow = wave * 16 + (lane >> 4) * 4;
  const int ncol = lane & 15;
  size_t base = (size_t)id * (kHP * kDS);
#pragma unroll
  for (int j = 0; j < 8; j++)
#pragma unroll
    for (int r = 0; r < 4; r++)
      states[base + (size_t)(prow + r) * kDS + j * 16 + ncol] = f2bu(acc[j][r]);
}

// ---- K5: sequential inter-chunk scan, ushort2 elements, prefetch depth 2
__global__ void scan_kernel(unsigned short* __restrict__ states,
                            const float* __restrict__ asum) {
  const int blk = blockIdx.x;
  const int seg = blk & 15;
  const int bh = blk >> 4;
  const int h = bh & 31, b = bh >> 5;
  const int e2 = seg * 256 + threadIdx.x;               // ushort2 index, 4096/(b,h)
  const size_t cstride = (size_t)kNH * 4096;            // ushort2 units per chunk
  ushort2* p = (ushort2*)states + ((size_t)(b * kNC) * kNH + h) * 4096 + e2;
  const float* ap = asum + (b * kNC) * kNH + h;
  float c0 = 0.f, c1 = 0.f;
  ushort2 t = p[0];
  float dec = expf(ap[0]);
  ushort2 t1v = p[cstride];                             // kNC >= 2 always
  float dec1 = expf(ap[kNH]);
  for (int c = 0; c < kNC; c++) {
    ushort2 t2v = t1v;
    float dec2 = dec1;
    if (c + 2 < kNC) {                                  // prefetch chunk c+2
      t2v = p[(size_t)(c + 2) * cstride];
      dec2 = expf(ap[(c + 2) * kNH]);
    }
    ushort2 o;
    o.x = f2bu(c0); o.y = f2bu(c1);
    p[(size_t)c * cstride] = o;
    c0 = c0 * dec + bu2f(t.x);
    c1 = c1 * dec + bu2f(t.y);
    t = t1v; dec = dec1;
    t1v = t2v; dec1 = dec2;
  }
}

// ---- K6: intra-chunk Y, 4 heads/block
__global__ __launch_bounds__(256) void y_kernel(
    const unsigned short* __restrict__ xbc_act,
    const unsigned short* __restrict__ zxbcdt,
    const unsigned short* __restrict__ states_in,
    const float* __restrict__ dtbuf,
    const float* __restrict__ A_log,
    unsigned short* __restrict__ ybuf,
    float* __restrict__ pS, float* __restrict__ pQ) {
  const int id = blockIdx.x;                 // (b*NC + c)*8 + hg
  const int hg = id & 7;
  const int c = (id >> 3) & (kNC - 1);
  const int b = id >> 9;
  const int tid = threadIdx.x;
  const int wave = tid >> 6, lane = tid & 63;
  __shared__ __align__(16) unsigned short sC[kCS * kTS];
  __shared__ __align__(16) unsigned short sB[kCS * kTS];
  __shared__ __align__(16) unsigned short sxd[kCS * kWS];
  __shared__ __align__(16) unsigned short sW[kCS * kWS];
  __shared__ float s_dt[4][kCS];
  __shared__ float s_acum[4][kCS];
  const int l0 = b * kL + c * kCS;
  {
    int hh = tid >> 6, s = tid & 63;
    s_dt[hh][s] = dtbuf[(size_t)(l0 + s) * kNH + hg * 4 + hh];
  }
  __syncthreads();
  {                                          // wave-parallel scan, one head/wave
    int hh = tid >> 6, s = tid & 63;
    float A = -expf(A_log[hg * 4 + hh]);
    float v = A * s_dt[hh][s];
#pragma unroll
    for (int off = 1; off < 64; off <<= 1) {
      float u = __shfl_up(v, off);
      if (s >= off) v += u;
    }
    s_acum[hh][s] = v;
  }
  for (int e = tid; e < kCS * 16; e += 256) {
    int row = e >> 4, c8 = (e & 15) * 8;
    size_t rb = (size_t)(l0 + row) * kConvDim;
    *(ushort8*)&sB[row * kTS + c8] = *(const ushort8*)&xbc_act[rb + kDI + c8];
    *(ushort8*)&sC[row * kTS + c8] = *(const ushort8*)&xbc_act[rb + kDI + kDS + c8];
  }
  __syncthreads();
  const int arow = wave * 16 + (lane & 15);
  const int fk = (lane >> 4) * 8;
  // G[l][s] = C . B^T  (K=128) — head-independent, once per block
  f32x4 accG[4] = {};
#pragma unroll
  for (int kk = 0; kk < 4; kk++) {
    bf16x8 a = *(const bf16x8*)&sC[arow * kTS + kk * 32 + fk];
#pragma unroll
    for (int j = 0; j < 4; j++) {
      bf16x8 bb = *(const bf16x8*)&sB[(j * 16 + (lane & 15)) * kTS + kk * 32 + fk];
      accG[j] = __builtin_amdgcn_mfma_f32_16x16x32_bf16(a, bb, accG[j], 0, 0, 0);
    }
  }
  const int lrow = wave * 16 + (lane >> 4) * 4;
  const size_t sbase = (size_t)((b * kNC + c) * kNH) * (kHP * kDS);
  float rS[4] = {}, rQ[4] = {};
  for (int hh = 0; hh < 4; hh++) {
    const int h = hg * 4 + hh;
    __syncthreads();   // prior iteration (or G) done reading sB/sxd/sW
    // stage xd^T for this head
    for (int e = tid; e < kCS * kHP; e += 256) {
      int s = e >> 6, p = e & 63;
      float xv = bu2f(xbc_act[(size_t)(l0 + s) * kConvDim + h * kHP + p]);
      sxd[p * kWS + s] = f2bu(xv * s_dt[hh][s]);
    }
    // W = mask(G)*decay  (wave-local strip)
#pragma unroll
    for (int j = 0; j < 4; j++) {
      int scol = j * 16 + (lane & 15);
      float as = s_acum[hh][scol];
#pragma unroll
      for (int r = 0; r < 4; r++) {
        int l = lrow + r;
        float w = (scol <= l) ? accG[j][r] * expf(s_acum[hh][l] - as) : 0.f;
        sW[l * kWS + scol] = f2bu(w);
      }
    }
    // stage Sin[p][n] for this head into sB
    for (int e = tid; e < kCS * 16; e += 256) {
      int row = e >> 4, c8 = (e & 15) * 8;
      *(ushort8*)&sB[row * kTS + c8] =
          *(const ushort8*)&states_in[sbase + (size_t)h * (kHP * kDS) + row * kDS + c8];
    }
    __syncthreads();
    // Yd = W . xd^T  (K=64)
    f32x4 accY[4] = {};
#pragma unroll
    for (int kk = 0; kk < 2; kk++) {
      bf16x8 a = *(const bf16x8*)&sW[arow * kWS + kk * 32 + fk];
#pragma unroll
      for (int j = 0; j < 4; j++) {
        bf16x8 bb = *(const bf16x8*)&sxd[(j * 16 + (lane & 15)) * kWS + kk * 32 + fk];
        accY[j] = __builtin_amdgcn_mfma_f32_16x16x32_bf16(a, bb, accY[j], 0, 0, 0);
      }
    }
    // Yoff = C . Sin^T  (K=128)
    f32x4 accO[4] = {};
#pragma unroll
    for (int kk = 0; kk < 4; kk++) {
      bf16x8 a = *(const bf16x8*)&sC[arow * kTS + kk * 32 + fk];
#pragma unroll
      for (int j = 0; j < 4; j++) {
        bf16x8 bb = *(const bf16x8*)&sB[(j * 16 + (lane & 15)) * kTS + kk * 32 + fk];
        accO[j] = __builtin_amdgcn_mfma_f32_16x16x32_bf16(a, bb, accO[j], 0, 0, 0);
      }
    }
#pragma unroll
    for (int r = 0; r < 4; r++) {
      int l = lrow + r;
      float el = expf(s_acum[hh][l]);
      size_t zrow = (size_t)(l0 + l) * kDProj + h * kHP;
      size_t yrow = (size_t)(l0 + l) * kDI + h * kHP;
#pragma unroll
      for (int j = 0; j < 4; j++) {
        int p = j * 16 + (lane & 15);
        float yv = accY[j][r] + el * accO[j][r];
        float z = bu2f(zxbcdt[zrow + p]);
        yv *= z / (1.f + expf(-z));
        rS[r] += yv;
        rQ[r] += yv * yv;
        ybuf[yrow + p] = f2bu(yv);
      }
    }
  }
#pragma unroll
  for (int m = 1; m < 16; m <<= 1) {
#pragma unroll
    for (int r = 0; r < 4; r++) {
      rS[r] += __shfl_xor(rS[r], m);
      rQ[r] += __shfl_xor(rQ[r], m);
    }
  }
  if ((lane & 15) == 0) {
#pragma unroll
    for (int r = 0; r < 4; r++) {
      int row = l0 + lrow + r;
      pS[(size_t)row * 8 + hg] = rS[r];
      pQ[(size_t)row * 8 + hg] = rQ[r];
    }
  }
}

// ---- K7: finalize LN stats from per-block partials
__global__ void ln_reduce(const float* __restrict__ pS, const float* __restrict__ pQ,
                          float* __restrict__ mu, float* __restrict__ rstd) {
  int row = blockIdx.x * 256 + threadIdx.x;
  if (row >= kRows) return;
  float s = 0.f, q = 0.f;
#pragma unroll
  for (int i = 0; i < 8; i++) { s += pS[(size_t)row * 8 + i]; q += pQ[(size_t)row * 8 + i]; }
  float m = s / kDI;
  mu[row] = m;
  rstd[row] = rsqrtf(q / kDI - m * m + kEps);
}

}  // namespace

extern "C" void kernel_launch(void* const* d_in, const int* in_sizes, int n_in,
                              void* d_out, int out_size, void* d_ws, size_t ws_size,
                              hipStream_t stream) {
  const float* u       = (const float*)d_in[0];
  const float* W_in    = (const float*)d_in[1];
  const float* conv_w  = (const float*)d_in[2];
  const float* conv_b  = (const float*)d_in[3];
  const float* dt_bias = (const float*)d_in[4];
  const float* A_log   = (const float*)d_in[5];
  const float* norm_w  = (const float*)d_in[6];
  const float* norm_b  = (const float*)d_in[7];
  const float* W_out   = (const float*)d_in[8];
  float* out = (float*)d_out;

  char* ws = (char*)d_ws;
  size_t off = 0;
  auto alloc = [&](size_t bytes) {
    void* p = ws + off;
    off += (bytes + 255) & ~(size_t)255;
    return p;
  };
  unsigned short* zxbcdt = (unsigned short*)alloc((size_t)kRows * kDProj * 2);        // 71.8 MB
  unsigned short* xbc    = (unsigned short*)alloc((size_t)kRows * kConvDim * 2);      // 37.7 MB
  float* dtb             = (float*)alloc((size_t)kRows * kNH * 4);                    //  1.0 MB
  float* asum            = (float*)alloc((size_t)kB * kNC * kNH * 4);                 // 16 KB
  unsigned short* A1     = (unsigned short*)alloc((size_t)kRows * 1024 * 2);          // 16.8 MB
  unsigned short* Bt1    = (unsigned short*)alloc((size_t)kDProjP * 1024 * 2);        //  9.2 MB
  unsigned short* states = (unsigned short*)alloc((size_t)kB * kNC * kNH * kHP * kDS * 2); // 67.1 MB
  unsigned short* Bt2    = (unsigned short*)alloc((size_t)1024 * kDI * 2);            //  4.2 MB
  unsigned short* ybuf   = (unsigned short*)alloc((size_t)kRows * kDI * 2);           // 33.6 MB
  float* mu              = (float*)alloc((size_t)kRows * 4);
  float* rstd            = (float*)alloc((size_t)kRows * 4);
  float* t1              = (float*)alloc(1024 * 4);
  float* t2              = (float*)alloc(1024 * 4);
  float* pS              = (float*)alloc((size_t)kRows * 8 * 4);                      // 256 KB
  float* pQ              = (float*)alloc((size_t)kRows * 8 * 4);                      // 256 KB
  (void)ws_size; (void)in_sizes; (void)n_in; (void)out_size;

  cast_kernel<<<(kRows * 1024 / 4 + 255) / 256, 256, 0, stream>>>(
      (const float4*)u, (ushort4*)A1, kRows * 1024 / 4);
  transpose_cast<<<dim3(kDProjP / 32, 1024 / 32), 256, 0, stream>>>(
      W_in, Bt1, 1024, kDProj, nullptr);
  transpose_cast<<<dim3(1024 / 32, 2048 / 32), 256, 0, stream>>>(
      W_out, Bt2, 2048, 1024, norm_w);
  colsum_kernel<<<16, 256, 0, stream>>>(W_out, norm_w, norm_b, t1, t2);
  gemm_bt<unsigned short, false><<<dim3(kDProjP / 128, kRows / 128), 256, 0, stream>>>(
      A1, Bt1, zxbcdt, kRows, kDProj, 1024, nullptr, nullptr, nullptr, nullptr,
      dt_bias, dtb);
  conv_silu_kernel<<<dim3(3, kRows / 8), 192, 0, stream>>>(zxbcdt, conv_w, conv_b, xbc);
  chunk_state_kernel<<<kB * kNC * kNH, 256, 0, stream>>>(xbc, dtb, A_log, states, asum);
  scan_kernel<<<kB * kNH * 16, 256, 0, stream>>>(states, asum);
  y_kernel<<<kB * kNC * 8, 256, 0, stream>>>(xbc, zxbcdt, states, dtb, A_log, ybuf, pS, pQ);
  ln_reduce<<<kRows / 256, 256, 0, stream>>>(pS, pQ, mu, rstd);
  gemm_bt<float, true><<<dim3(1024 / 128, kRows / 128), 256, 0, stream>>>(
      ybuf, Bt2, out, kRows, 1024, 2048, mu, rstd, t1, t2, nullptr, nullptr);
}

// Round 5
// 437.234 us; speedup vs baseline: 1.0092x; 1.0092x over previous
//
#include <hip/hip_runtime.h>
#include <hip/hip_bf16.h>
#include <math.h>

// ---------------------------------------------------------------------------
// Mamba2 forward, MI355X. Round 14: revert the dt-softplus GEMM-epilogue
// fusion (round-13's only GEMM1 change; it cost ~14us on GEMM1: MfmaUtil
// 36->31, dur 89->103, while saving only ~4us of dt dispatch). GEMM1 is
// bit-identical to round 12 (89us, MfmaUtil 36%). Separate dt_kernel is back.
// Mid-pipeline basket from round 13 kept:
//   - scan: ushort2 elements (2x waves) + prefetch-2.
//   - chunk_state / y_kernel: wave-parallel shfl_up cumsum.
//   - conv_silu: block 192 (exact 576-thread fit).
// ---------------------------------------------------------------------------

namespace {

constexpr int kB   = 2;
constexpr int kL   = 4096;
constexpr int kDI  = 2048;
constexpr int kDS  = 128;
constexpr int kNH  = 32;
constexpr int kHP  = 64;
constexpr int kDC  = 4;
constexpr int kCS  = 64;
constexpr int kNC  = kL / kCS;
constexpr int kDProj   = 2 * kDI + 2 * kDS + kNH;  // 4384
constexpr int kDProjP  = 4480;                     // 35*128
constexpr int kConvDim = kDI + 2 * kDS;            // 2304
constexpr int kRows = kB * kL;                     // 8192
constexpr float kEps = 1e-5f;
constexpr int kTS = 136;   // LDS stride for [64][128] tiles
constexpr int kWS = 72;    // LDS stride for [64][64] tiles

typedef __bf16 bf16x8 __attribute__((ext_vector_type(8)));
typedef float f32x4 __attribute__((ext_vector_type(4)));
typedef unsigned short ushort8 __attribute__((ext_vector_type(8)));

__device__ inline float bu2f(unsigned short u) {
  union { unsigned int i; float f; } x; x.i = ((unsigned int)u) << 16; return x.f;
}
__device__ inline unsigned short f2bu(float f) {
  __hip_bfloat16 h = __float2bfloat16(f);
  return *reinterpret_cast<unsigned short*>(&h);
}

__device__ inline void store_out(float* C, size_t i, float v) { C[i] = v; }
__device__ inline void store_out(unsigned short* C, size_t i, float v) { C[i] = f2bu(v); }

__device__ inline void gld_lds16(const unsigned short* g, unsigned short* l) {
  __builtin_amdgcn_global_load_lds(
      (const __attribute__((address_space(1))) unsigned int*)g,
      (__attribute__((address_space(3))) unsigned int*)l, 16, 0, 0);
}

// ---- C0: cast fp32 -> bf16
__global__ void cast_kernel(const float4* __restrict__ in, ushort4* __restrict__ out, int n4) {
  int i = blockIdx.x * 256 + threadIdx.x;
  if (i >= n4) return;
  float4 v = in[i];
  ushort4 o;
  o.x = f2bu(v.x); o.y = f2bu(v.y); o.z = f2bu(v.z); o.w = f2bu(v.w);
  out[i] = o;
}

// ---- C1/C2: transpose + cast (+optional per-row scale)
__global__ void transpose_cast(const float* __restrict__ in, unsigned short* __restrict__ out,
                               int R, int C, const float* __restrict__ scale) {
  __shared__ float t[32][33];
  const int c0 = blockIdx.x * 32;
  const int r0 = blockIdx.y * 32;
  const int tx = threadIdx.x & 31, ty = threadIdx.x >> 5;
  for (int rr = ty; rr < 32; rr += 8) {
    int c = c0 + tx;
    float v = (c < C) ? in[(size_t)(r0 + rr) * C + c] : 0.f;
    if (scale) v *= scale[r0 + rr];
    t[rr][tx] = v;
  }
  __syncthreads();
  for (int cc = ty; cc < 32; cc += 8) {
    int orow = c0 + cc;
    out[(size_t)orow * R + r0 + tx] = f2bu(t[tx][cc]);
  }
}

// ---- C3: t1[n] = sum_k w[k]*W2[k][n], t2[n] = sum_k b[k]*W2[k][n]
__global__ void colsum_kernel(const float* __restrict__ W2, const float* __restrict__ wv,
                              const float* __restrict__ bv,
                              float* __restrict__ t1, float* __restrict__ t2) {
  __shared__ float p1[4][64], p2[4][64];
  const int nl = threadIdx.x & 63;
  const int ks = threadIdx.x >> 6;
  const int n = blockIdx.x * 64 + nl;
  float s1 = 0.f, s2 = 0.f;
  for (int k = ks * 512; k < ks * 512 + 512; k++) {
    float v = W2[(size_t)k * 1024 + n];
    s1 += wv[k] * v;
    s2 += bv[k] * v;
  }
  p1[ks][nl] = s1; p2[ks][nl] = s2;
  __syncthreads();
  if (threadIdx.x < 64) {
    t1[blockIdx.x * 64 + threadIdx.x] =
        p1[0][threadIdx.x] + p1[1][threadIdx.x] + p1[2][threadIdx.x] + p1[3][threadIdx.x];
    t2[blockIdx.x * 64 + threadIdx.x] =
        p2[0][threadIdx.x] + p2[1][threadIdx.x] + p2[2][threadIdx.x] + p2[3][threadIdx.x];
  }
}

// ---- MFMA GEMM, 128x128 tile, BK=64, XOR-swizzled LDS, XCD-swizzled grid.
// FOLD applies LayerNorm in epilogue.  (bit-identical to round 12)
template <typename OutT, bool FOLD>
__global__ __launch_bounds__(256, 3) void gemm_bt(const unsigned short* __restrict__ A,
                                                  const unsigned short* __restrict__ Bt,
                                                  OutT* __restrict__ C, int M, int N, int K,
                                                  const float* __restrict__ mu,
                                                  const float* __restrict__ rstd,
                                                  const float* __restrict__ t1,
                                                  const float* __restrict__ t2) {
  __shared__ __align__(16) unsigned short As[128 * 64];   // 16 KB
  __shared__ __align__(16) unsigned short Bs[128 * 64];   // 16 KB
  const int tid = threadIdx.x;
  const int wave = tid >> 6, lane = tid & 63;
  // T1: bijective XCD swizzle (both grids are multiples of 8)
  const int nwg = (int)(gridDim.x * gridDim.y);
  const int orig = (int)(blockIdx.y * gridDim.x + blockIdx.x);
  const int swz = (orig & 7) * (nwg >> 3) + (orig >> 3);
  const int bx = swz % (int)gridDim.x, by = swz / (int)gridDim.x;
  const int m0 = by * 128, n0 = bx * 128;
  const int wr = (wave >> 1) * 64, wc = (wave & 1) * 64;
  // staging: LDS[row][s] holds global[row][s ^ (row&7)] (dest linear, source
  // pre-swizzled; read slot ^ (row&7)).
  const int l8 = lane >> 3, s8 = lane & 7;
  const unsigned short* pA[4];
  const unsigned short* pB[4];
  unsigned short* lA[4];
  unsigned short* lB[4];
#pragma unroll
  for (int r = 0; r < 4; r++) {
    int q = wave * 4 + r;                       // 16 segments x 8 rows = 128 rows
    pA[r] = A + (size_t)(m0 + q * 8 + l8) * K + (s8 ^ l8) * 8;
    pB[r] = Bt + (size_t)(n0 + q * 8 + l8) * K + (s8 ^ l8) * 8;
    lA[r] = &As[q * 512];
    lB[r] = &Bs[q * 512];
  }
  const int fr = lane & 15;
  const int c4 = lane >> 4;
  const int sk0 = (c4 ^ (fr & 7)) * 8;          // kk=0: slots 0..3, swizzled
  const int sk1 = ((4 | c4) ^ (fr & 7)) * 8;    // kk=1: slots 4..7, swizzled
  f32x4 acc[4][4] = {};
  for (int k0 = 0; k0 < K; k0 += 64) {
#pragma unroll
    for (int r = 0; r < 4; r++) {
      gld_lds16(pA[r] + k0, lA[r]);
      gld_lds16(pB[r] + k0, lB[r]);
    }
    asm volatile("s_waitcnt vmcnt(0)" ::: "memory");
    __syncthreads();
    {
      bf16x8 af0[4], bf0[4];
#pragma unroll
      for (int i = 0; i < 4; i++) {
        af0[i] = *(const bf16x8*)&As[(wr + i * 16 + fr) * 64 + sk0];
        bf0[i] = *(const bf16x8*)&Bs[(wc + i * 16 + fr) * 64 + sk0];
      }
#pragma unroll
      for (int i = 0; i < 4; i++)
#pragma unroll
        for (int j = 0; j < 4; j++)
          acc[i][j] = __builtin_amdgcn_mfma_f32_16x16x32_bf16(af0[i], bf0[j], acc[i][j], 0, 0, 0);
    }
    {
      bf16x8 af1[4], bf1[4];
#pragma unroll
      for (int i = 0; i < 4; i++) {
        af1[i] = *(const bf16x8*)&As[(wr + i * 16 + fr) * 64 + sk1];
        bf1[i] = *(const bf16x8*)&Bs[(wc + i * 16 + fr) * 64 + sk1];
      }
#pragma unroll
      for (int i = 0; i < 4; i++)
#pragma unroll
        for (int j = 0; j < 4; j++)
          acc[i][j] = __builtin_amdgcn_mfma_f32_16x16x32_bf16(af1[i], bf1[j], acc[i][j], 0, 0, 0);
    }
    __syncthreads();
  }
  const int crow = (lane >> 4) * 4;
  const int ccol = lane & 15;
#pragma unroll
  for (int i = 0; i < 4; i++) {
#pragma unroll
    for (int j = 0; j < 4; j++) {
      int n = n0 + wc + j * 16 + ccol;
      if (n < N) {
        float c1 = FOLD ? t1[n] : 0.f;
        float c2 = FOLD ? t2[n] : 0.f;
#pragma unroll
        for (int r = 0; r < 4; r++) {
          int m = m0 + wr + i * 16 + crow + r;
          float v = acc[i][j][r];
          if (FOLD) v = rstd[m] * (v - mu[m] * c1) + c2;
          store_out(C, (size_t)m * N + n, v);
        }
      }
    }
  }
}

// ---- K2: dt = softplus(dt_raw + dt_bias)
__global__ void dt_kernel(const unsigned short* __restrict__ zxbcdt,
                          const float* __restrict__ dt_bias,
                          float* __restrict__ dtbuf) {
  int idx = blockIdx.x * 256 + threadIdx.x;
  if (idx >= kRows * kNH) return;
  int row = idx >> 5, h = idx & 31;
  float x = bu2f(zxbcdt[(size_t)row * kDProj + (kDProj - kNH) + h]) + dt_bias[h];
  dtbuf[idx] = (x > 15.f) ? x : log1pf(expf(x));
}

// ---- K3: causal depthwise conv (k=4) + SiLU, 8 rows x 4 cols per thread
__global__ void conv_silu_kernel(const unsigned short* __restrict__ zxbcdt,
                                 const float* __restrict__ conv_w,
                                 const float* __restrict__ conv_b,
                                 unsigned short* __restrict__ xbc_act) {
  int c4 = blockIdx.x * 192 + threadIdx.x;
  if (c4 >= kConvDim / 4) return;
  const int c = c4 * 4;
  const int r0 = blockIdx.y * 8;
  const int l0 = r0 & (kL - 1);
  float4 w[4];
  float bias[4];
#pragma unroll
  for (int q = 0; q < 4; q++) {
    w[q] = ((const float4*)conv_w)[c + q];
    bias[q] = conv_b[c + q];
  }
  float v[11][4];
#pragma unroll
  for (int i = 0; i < 11; i++) {
    int l = l0 - 3 + i;
    if (l >= 0) {
      ushort4 t = *(const ushort4*)&zxbcdt[(size_t)(r0 - 3 + i) * kDProj + kDI + c];
      v[i][0] = bu2f(t.x); v[i][1] = bu2f(t.y); v[i][2] = bu2f(t.z); v[i][3] = bu2f(t.w);
    } else {
      v[i][0] = v[i][1] = v[i][2] = v[i][3] = 0.f;
    }
  }
#pragma unroll
  for (int j = 0; j < 8; j++) {
    ushort4 o;
    unsigned short* op = (unsigned short*)&o;
#pragma unroll
    for (int q = 0; q < 4; q++) {
      float a = bias[q] + v[j][q] * w[q].x + v[j + 1][q] * w[q].y +
                v[j + 2][q] * w[q].z + v[j + 3][q] * w[q].w;
      op[q] = f2bu(a / (1.f + expf(-a)));
    }
    *(ushort4*)&xbc_act[(size_t)(r0 + j) * kConvDim + c] = o;
  }
}

// ---- K4: per-(b,chunk,head) end-of-chunk state via MFMA
__global__ __launch_bounds__(256) void chunk_state_kernel(
    const unsigned short* __restrict__ xbc_act,
    const float* __restrict__ dtbuf,
    const float* __restrict__ A_log,
    unsigned short* __restrict__ states,
    float* __restrict__ asum) {
  const int id = blockIdx.x;
  const int h = id & 31;
  const int c = (id >> 5) & (kNC - 1);
  const int b = id >> 11;
  const int tid = threadIdx.x;
  const int wave = tid >> 6, lane = tid & 63;
  __shared__ __align__(16) unsigned short sBT[kDS * kWS];
  __shared__ __align__(16) unsigned short sxd[kCS * kWS];
  __shared__ float s_dt[kCS];
  __shared__ float s_acum[kCS];
  const int l0 = b * kL + c * kCS;
  if (tid < kCS) s_dt[tid] = dtbuf[(size_t)(l0 + tid) * kNH + h];
  __syncthreads();
  if (tid < 64) {                      // wave-parallel inclusive scan
    float A = -expf(A_log[h]);
    float v = A * s_dt[tid];
#pragma unroll
    for (int off = 1; off < 64; off <<= 1) {
      float u = __shfl_up(v, off);
      if (tid >= off) v += u;
    }
    s_acum[tid] = v;
    if (tid == 63) asum[id] = v;
  }
  __syncthreads();
  const float total = s_acum[kCS - 1];
  for (int e = tid; e < kCS * kDS; e += 256) {
    int s = e >> 7, n = e & 127;
    sBT[n * kWS + s] = xbc_act[(size_t)(l0 + s) * kConvDim + kDI + n];
  }
  for (int e = tid; e < kCS * kHP; e += 256) {
    int s = e >> 6, p = e & 63;
    float xv = bu2f(xbc_act[(size_t)(l0 + s) * kConvDim + h * kHP + p]);
    sxd[p * kWS + s] = f2bu(xv * s_dt[s] * expf(total - s_acum[s]));
  }
  __syncthreads();
  const int arow = wave * 16 + (lane & 15);
  const int fk = (lane >> 4) * 8;
  f32x4 acc[8] = {};
#pragma unroll
  for (int kk = 0; kk < 2; kk++) {
    bf16x8 a = *(const bf16x8*)&sxd[arow * kWS + kk * 32 + fk];
#pragma unroll
    for (int j = 0; j < 8; j++) {
      bf16x8 bb = *(const bf16x8*)&sBT[(j * 16 + (lane & 15)) * kWS + kk * 32 + fk];
      acc[j] = __builtin_amdgcn_mfma_f32_16x16x32_bf16(a, bb, acc[j], 0, 0, 0);
    }
  }
  const int prow = wave * 16 + (lane >> 4) * 4;
  const int ncol = lane & 15;
  size_t base = (size_t)id * (kHP * kDS);
#pragma unroll
  for (int j = 0; j < 8; j++)
#pragma unroll
    for (int r = 0; r < 4; r++)
      states[base + (size_t)(prow + r) * kDS + j * 16 + ncol] = f2bu(acc[j][r]);
}

// ---- K5: sequential inter-chunk scan, ushort2 elements, prefetch depth 2
__global__ void scan_kernel(unsigned short* __restrict__ states,
                            const float* __restrict__ asum) {
  const int blk = blockIdx.x;
  const int seg = blk & 15;
  const int bh = blk >> 4;
  const int h = bh & 31, b = bh >> 5;
  const int e2 = seg * 256 + threadIdx.x;               // ushort2 index, 4096/(b,h)
  const size_t cstride = (size_t)kNH * 4096;            // ushort2 units per chunk
  ushort2* p = (ushort2*)states + ((size_t)(b * kNC) * kNH + h) * 4096 + e2;
  const float* ap = asum + (b * kNC) * kNH + h;
  float c0 = 0.f, c1 = 0.f;
  ushort2 t = p[0];
  float dec = expf(ap[0]);
  ushort2 t1v = p[cstride];                             // kNC >= 2 always
  float dec1 = expf(ap[kNH]);
  for (int c = 0; c < kNC; c++) {
    ushort2 t2v = t1v;
    float dec2 = dec1;
    if (c + 2 < kNC) {                                  // prefetch chunk c+2
      t2v = p[(size_t)(c + 2) * cstride];
      dec2 = expf(ap[(c + 2) * kNH]);
    }
    ushort2 o;
    o.x = f2bu(c0); o.y = f2bu(c1);
    p[(size_t)c * cstride] = o;
    c0 = c0 * dec + bu2f(t.x);
    c1 = c1 * dec + bu2f(t.y);
    t = t1v; dec = dec1;
    t1v = t2v; dec1 = dec2;
  }
}

// ---- K6: intra-chunk Y, 4 heads/block
__global__ __launch_bounds__(256) void y_kernel(
    const unsigned short* __restrict__ xbc_act,
    const unsigned short* __restrict__ zxbcdt,
    const unsigned short* __restrict__ states_in,
    const float* __restrict__ dtbuf,
    const float* __restrict__ A_log,
    unsigned short* __restrict__ ybuf,
    float* __restrict__ pS, float* __restrict__ pQ) {
  const int id = blockIdx.x;                 // (b*NC + c)*8 + hg
  const int hg = id & 7;
  const int c = (id >> 3) & (kNC - 1);
  const int b = id >> 9;
  const int tid = threadIdx.x;
  const int wave = tid >> 6, lane = tid & 63;
  __shared__ __align__(16) unsigned short sC[kCS * kTS];
  __shared__ __align__(16) unsigned short sB[kCS * kTS];
  __shared__ __align__(16) unsigned short sxd[kCS * kWS];
  __shared__ __align__(16) unsigned short sW[kCS * kWS];
  __shared__ float s_dt[4][kCS];
  __shared__ float s_acum[4][kCS];
  const int l0 = b * kL + c * kCS;
  {
    int hh = tid >> 6, s = tid & 63;
    s_dt[hh][s] = dtbuf[(size_t)(l0 + s) * kNH + hg * 4 + hh];
  }
  __syncthreads();
  {                                          // wave-parallel scan, one head/wave
    int hh = tid >> 6, s = tid & 63;
    float A = -expf(A_log[hg * 4 + hh]);
    float v = A * s_dt[hh][s];
#pragma unroll
    for (int off = 1; off < 64; off <<= 1) {
      float u = __shfl_up(v, off);
      if (s >= off) v += u;
    }
    s_acum[hh][s] = v;
  }
  for (int e = tid; e < kCS * 16; e += 256) {
    int row = e >> 4, c8 = (e & 15) * 8;
    size_t rb = (size_t)(l0 + row) * kConvDim;
    *(ushort8*)&sB[row * kTS + c8] = *(const ushort8*)&xbc_act[rb + kDI + c8];
    *(ushort8*)&sC[row * kTS + c8] = *(const ushort8*)&xbc_act[rb + kDI + kDS + c8];
  }
  __syncthreads();
  const int arow = wave * 16 + (lane & 15);
  const int fk = (lane >> 4) * 8;
  // G[l][s] = C . B^T  (K=128) — head-independent, once per block
  f32x4 accG[4] = {};
#pragma unroll
  for (int kk = 0; kk < 4; kk++) {
    bf16x8 a = *(const bf16x8*)&sC[arow * kTS + kk * 32 + fk];
#pragma unroll
    for (int j = 0; j < 4; j++) {
      bf16x8 bb = *(const bf16x8*)&sB[(j * 16 + (lane & 15)) * kTS + kk * 32 + fk];
      accG[j] = __builtin_amdgcn_mfma_f32_16x16x32_bf16(a, bb, accG[j], 0, 0, 0);
    }
  }
  const int lrow = wave * 16 + (lane >> 4) * 4;
  const size_t sbase = (size_t)((b * kNC + c) * kNH) * (kHP * kDS);
  float rS[4] = {}, rQ[4] = {};
  for (int hh = 0; hh < 4; hh++) {
    const int h = hg * 4 + hh;
    __syncthreads();   // prior iteration (or G) done reading sB/sxd/sW
    // stage xd^T for this head
    for (int e = tid; e < kCS * kHP; e += 256) {
      int s = e >> 6, p = e & 63;
      float xv = bu2f(xbc_act[(size_t)(l0 + s) * kConvDim + h * kHP + p]);
      sxd[p * kWS + s] = f2bu(xv * s_dt[hh][s]);
    }
    // W = mask(G)*decay  (wave-local strip)
#pragma unroll
    for (int j = 0; j < 4; j++) {
      int scol = j * 16 + (lane & 15);
      float as = s_acum[hh][scol];
#pragma unroll
      for (int r = 0; r < 4; r++) {
        int l = lrow + r;
        float w = (scol <= l) ? accG[j][r] * expf(s_acum[hh][l] - as) : 0.f;
        sW[l * kWS + scol] = f2bu(w);
      }
    }
    // stage Sin[p][n] for this head into sB
    for (int e = tid; e < kCS * 16; e += 256) {
      int row = e >> 4, c8 = (e & 15) * 8;
      *(ushort8*)&sB[row * kTS + c8] =
          *(const ushort8*)&states_in[sbase + (size_t)h * (kHP * kDS) + row * kDS + c8];
    }
    __syncthreads();
    // Yd = W . xd^T  (K=64)
    f32x4 accY[4] = {};
#pragma unroll
    for (int kk = 0; kk < 2; kk++) {
      bf16x8 a = *(const bf16x8*)&sW[arow * kWS + kk * 32 + fk];
#pragma unroll
      for (int j = 0; j < 4; j++) {
        bf16x8 bb = *(const bf16x8*)&sxd[(j * 16 + (lane & 15)) * kWS + kk * 32 + fk];
        accY[j] = __builtin_amdgcn_mfma_f32_16x16x32_bf16(a, bb, accY[j], 0, 0, 0);
      }
    }
    // Yoff = C . Sin^T  (K=128)
    f32x4 accO[4] = {};
#pragma unroll
    for (int kk = 0; kk < 4; kk++) {
      bf16x8 a = *(const bf16x8*)&sC[arow * kTS + kk * 32 + fk];
#pragma unroll
      for (int j = 0; j < 4; j++) {
        bf16x8 bb = *(const bf16x8*)&sB[(j * 16 + (lane & 15)) * kTS + kk * 32 + fk];
        accO[j] = __builtin_amdgcn_mfma_f32_16x16x32_bf16(a, bb, accO[j], 0, 0, 0);
      }
    }
#pragma unroll
    for (int r = 0; r < 4; r++) {
      int l = lrow + r;
      float el = expf(s_acum[hh][l]);
      size_t zrow = (size_t)(l0 + l) * kDProj + h * kHP;
      size_t yrow = (size_t)(l0 + l) * kDI + h * kHP;
#pragma unroll
      for (int j = 0; j < 4; j++) {
        int p = j * 16 + (lane & 15);
        float yv = accY[j][r] + el * accO[j][r];
        float z = bu2f(zxbcdt[zrow + p]);
        yv *= z / (1.f + expf(-z));
        rS[r] += yv;
        rQ[r] += yv * yv;
        ybuf[yrow + p] = f2bu(yv);
      }
    }
  }
#pragma unroll
  for (int m = 1; m < 16; m <<= 1) {
#pragma unroll
    for (int r = 0; r < 4; r++) {
      rS[r] += __shfl_xor(rS[r], m);
      rQ[r] += __shfl_xor(rQ[r], m);
    }
  }
  if ((lane & 15) == 0) {
#pragma unroll
    for (int r = 0; r < 4; r++) {
      int row = l0 + lrow + r;
      pS[(size_t)row * 8 + hg] = rS[r];
      pQ[(size_t)row * 8 + hg] = rQ[r];
    }
  }
}

// ---- K7: finalize LN stats from per-block partials
__global__ void ln_reduce(const float* __restrict__ pS, const float* __restrict__ pQ,
                          float* __restrict__ mu, float* __restrict__ rstd) {
  int row = blockIdx.x * 256 + threadIdx.x;
  if (row >= kRows) return;
  float s = 0.f, q = 0.f;
#pragma unroll
  for (int i = 0; i < 8; i++) { s += pS[(size_t)row * 8 + i]; q += pQ[(size_t)row * 8 + i]; }
  float m = s / kDI;
  mu[row] = m;
  rstd[row] = rsqrtf(q / kDI - m * m + kEps);
}

}  // namespace

extern "C" void kernel_launch(void* const* d_in, const int* in_sizes, int n_in,
                              void* d_out, int out_size, void* d_ws, size_t ws_size,
                              hipStream_t stream) {
  const float* u       = (const float*)d_in[0];
  const float* W_in    = (const float*)d_in[1];
  const float* conv_w  = (const float*)d_in[2];
  const float* conv_b  = (const float*)d_in[3];
  const float* dt_bias = (const float*)d_in[4];
  const float* A_log   = (const float*)d_in[5];
  const float* norm_w  = (const float*)d_in[6];
  const float* norm_b  = (const float*)d_in[7];
  const float* W_out   = (const float*)d_in[8];
  float* out = (float*)d_out;

  char* ws = (char*)d_ws;
  size_t off = 0;
  auto alloc = [&](size_t bytes) {
    void* p = ws + off;
    off += (bytes + 255) & ~(size_t)255;
    return p;
  };
  unsigned short* zxbcdt = (unsigned short*)alloc((size_t)kRows * kDProj * 2);        // 71.8 MB
  unsigned short* xbc    = (unsigned short*)alloc((size_t)kRows * kConvDim * 2);      // 37.7 MB
  float* dtb             = (float*)alloc((size_t)kRows * kNH * 4);                    //  1.0 MB
  float* asum            = (float*)alloc((size_t)kB * kNC * kNH * 4);                 // 16 KB
  unsigned short* A1     = (unsigned short*)alloc((size_t)kRows * 1024 * 2);          // 16.8 MB
  unsigned short* Bt1    = (unsigned short*)alloc((size_t)kDProjP * 1024 * 2);        //  9.2 MB
  unsigned short* states = (unsigned short*)alloc((size_t)kB * kNC * kNH * kHP * kDS * 2); // 67.1 MB
  unsigned short* Bt2    = (unsigned short*)alloc((size_t)1024 * kDI * 2);            //  4.2 MB
  unsigned short* ybuf   = (unsigned short*)alloc((size_t)kRows * kDI * 2);           // 33.6 MB
  float* mu              = (float*)alloc((size_t)kRows * 4);
  float* rstd            = (float*)alloc((size_t)kRows * 4);
  float* t1              = (float*)alloc(1024 * 4);
  float* t2              = (float*)alloc(1024 * 4);
  float* pS              = (float*)alloc((size_t)kRows * 8 * 4);                      // 256 KB
  float* pQ              = (float*)alloc((size_t)kRows * 8 * 4);                      // 256 KB
  (void)ws_size; (void)in_sizes; (void)n_in; (void)out_size;

  cast_kernel<<<(kRows * 1024 / 4 + 255) / 256, 256, 0, stream>>>(
      (const float4*)u, (ushort4*)A1, kRows * 1024 / 4);
  transpose_cast<<<dim3(kDProjP / 32, 1024 / 32), 256, 0, stream>>>(
      W_in, Bt1, 1024, kDProj, nullptr);
  transpose_cast<<<dim3(1024 / 32, 2048 / 32), 256, 0, stream>>>(
      W_out, Bt2, 2048, 1024, norm_w);
  colsum_kernel<<<16, 256, 0, stream>>>(W_out, norm_w, norm_b, t1, t2);
  gemm_bt<unsigned short, false><<<dim3(kDProjP / 128, kRows / 128), 256, 0, stream>>>(
      A1, Bt1, zxbcdt, kRows, kDProj, 1024, nullptr, nullptr, nullptr, nullptr);
  dt_kernel<<<(kRows * kNH + 255) / 256, 256, 0, stream>>>(zxbcdt, dt_bias, dtb);
  conv_silu_kernel<<<dim3(3, kRows / 8), 192, 0, stream>>>(zxbcdt, conv_w, conv_b, xbc);
  chunk_state_kernel<<<kB * kNC * kNH, 256, 0, stream>>>(xbc, dtb, A_log, states, asum);
  scan_kernel<<<kB * kNH * 16, 256, 0, stream>>>(states, asum);
  y_kernel<<<kB * kNC * 8, 256, 0, stream>>>(xbc, zxbcdt, states, dtb, A_log, ybuf, pS, pQ);
  ln_reduce<<<kRows / 256, 256, 0, stream>>>(pS, pQ, mu, rstd);
  gemm_bt<float, true><<<dim3(1024 / 128, kRows / 128), 256, 0, stream>>>(
      ybuf, Bt2, out, kRows, 1024, 2048, mu, rstd, t1, t2);
}

// Round 6
// 418.716 us; speedup vs baseline: 1.0539x; 1.0442x over previous
//
#include <hip/hip_runtime.h>
#include <hip/hip_bf16.h>
#include <math.h>

// ---------------------------------------------------------------------------
// Mamba2 forward, MI355X. Round 15: keep round-14 structure (GEMM1 at 89us
// verified). Three bounded levers:
//   - gemm_bt __launch_bounds__(256,3)->(256,4): 4 blocks/CU (VGPR 64,
//     LDS 32KB fit) -> +33% resident waves to overlap the per-K-step
//     vmcnt(0)+barrier drain (m114 mechanism).
//   - dt_kernel merged into conv_silu (bx==0 computes its rows' softplus).
//   - y/chunk_state LDS strides kTS 136->130, kWS 72->68: y_kernel LDS
//     55->52.7KB -> 3 blocks/CU; transposed scalar staging writes improve
//     8-way -> 4-way bank aliasing. Frag reads stay <=2-way (checked).
// ---------------------------------------------------------------------------

namespace {

constexpr int kB   = 2;
constexpr int kL   = 4096;
constexpr int kDI  = 2048;
constexpr int kDS  = 128;
constexpr int kNH  = 32;
constexpr int kHP  = 64;
constexpr int kDC  = 4;
constexpr int kCS  = 64;
constexpr int kNC  = kL / kCS;
constexpr int kDProj   = 2 * kDI + 2 * kDS + kNH;  // 4384
constexpr int kDProjP  = 4480;                     // 35*128
constexpr int kConvDim = kDI + 2 * kDS;            // 2304
constexpr int kRows = kB * kL;                     // 8192
constexpr float kEps = 1e-5f;
constexpr int kTS = 130;   // LDS stride for [64][128] tiles (bank +1/row)
constexpr int kWS = 68;    // LDS stride for [64][64] tiles  (bank +2/row)

typedef __bf16 bf16x8 __attribute__((ext_vector_type(8)));
typedef float f32x4 __attribute__((ext_vector_type(4)));
typedef unsigned short ushort8 __attribute__((ext_vector_type(8)));

__device__ inline float bu2f(unsigned short u) {
  union { unsigned int i; float f; } x; x.i = ((unsigned int)u) << 16; return x.f;
}
__device__ inline unsigned short f2bu(float f) {
  __hip_bfloat16 h = __float2bfloat16(f);
  return *reinterpret_cast<unsigned short*>(&h);
}

__device__ inline void store_out(float* C, size_t i, float v) { C[i] = v; }
__device__ inline void store_out(unsigned short* C, size_t i, float v) { C[i] = f2bu(v); }

__device__ inline void gld_lds16(const unsigned short* g, unsigned short* l) {
  __builtin_amdgcn_global_load_lds(
      (const __attribute__((address_space(1))) unsigned int*)g,
      (__attribute__((address_space(3))) unsigned int*)l, 16, 0, 0);
}

// ---- C0: cast fp32 -> bf16
__global__ void cast_kernel(const float4* __restrict__ in, ushort4* __restrict__ out, int n4) {
  int i = blockIdx.x * 256 + threadIdx.x;
  if (i >= n4) return;
  float4 v = in[i];
  ushort4 o;
  o.x = f2bu(v.x); o.y = f2bu(v.y); o.z = f2bu(v.z); o.w = f2bu(v.w);
  out[i] = o;
}

// ---- C1/C2: transpose + cast (+optional per-row scale)
__global__ void transpose_cast(const float* __restrict__ in, unsigned short* __restrict__ out,
                               int R, int C, const float* __restrict__ scale) {
  __shared__ float t[32][33];
  const int c0 = blockIdx.x * 32;
  const int r0 = blockIdx.y * 32;
  const int tx = threadIdx.x & 31, ty = threadIdx.x >> 5;
  for (int rr = ty; rr < 32; rr += 8) {
    int c = c0 + tx;
    float v = (c < C) ? in[(size_t)(r0 + rr) * C + c] : 0.f;
    if (scale) v *= scale[r0 + rr];
    t[rr][tx] = v;
  }
  __syncthreads();
  for (int cc = ty; cc < 32; cc += 8) {
    int orow = c0 + cc;
    out[(size_t)orow * R + r0 + tx] = f2bu(t[tx][cc]);
  }
}

// ---- C3: t1[n] = sum_k w[k]*W2[k][n], t2[n] = sum_k b[k]*W2[k][n]
__global__ void colsum_kernel(const float* __restrict__ W2, const float* __restrict__ wv,
                              const float* __restrict__ bv,
                              float* __restrict__ t1, float* __restrict__ t2) {
  __shared__ float p1[4][64], p2[4][64];
  const int nl = threadIdx.x & 63;
  const int ks = threadIdx.x >> 6;
  const int n = blockIdx.x * 64 + nl;
  float s1 = 0.f, s2 = 0.f;
  for (int k = ks * 512; k < ks * 512 + 512; k++) {
    float v = W2[(size_t)k * 1024 + n];
    s1 += wv[k] * v;
    s2 += bv[k] * v;
  }
  p1[ks][nl] = s1; p2[ks][nl] = s2;
  __syncthreads();
  if (threadIdx.x < 64) {
    t1[blockIdx.x * 64 + threadIdx.x] =
        p1[0][threadIdx.x] + p1[1][threadIdx.x] + p1[2][threadIdx.x] + p1[3][threadIdx.x];
    t2[blockIdx.x * 64 + threadIdx.x] =
        p2[0][threadIdx.x] + p2[1][threadIdx.x] + p2[2][threadIdx.x] + p2[3][threadIdx.x];
  }
}

// ---- MFMA GEMM, 128x128 tile, BK=64, XOR-swizzled LDS, XCD-swizzled grid.
// FOLD applies LayerNorm in epilogue.  (round-12 main loop; occupancy 4)
template <typename OutT, bool FOLD>
__global__ __launch_bounds__(256, 4) void gemm_bt(const unsigned short* __restrict__ A,
                                                  const unsigned short* __restrict__ Bt,
                                                  OutT* __restrict__ C, int M, int N, int K,
                                                  const float* __restrict__ mu,
                                                  const float* __restrict__ rstd,
                                                  const float* __restrict__ t1,
                                                  const float* __restrict__ t2) {
  __shared__ __align__(16) unsigned short As[128 * 64];   // 16 KB
  __shared__ __align__(16) unsigned short Bs[128 * 64];   // 16 KB
  const int tid = threadIdx.x;
  const int wave = tid >> 6, lane = tid & 63;
  // T1: bijective XCD swizzle (both grids are multiples of 8)
  const int nwg = (int)(gridDim.x * gridDim.y);
  const int orig = (int)(blockIdx.y * gridDim.x + blockIdx.x);
  const int swz = (orig & 7) * (nwg >> 3) + (orig >> 3);
  const int bx = swz % (int)gridDim.x, by = swz / (int)gridDim.x;
  const int m0 = by * 128, n0 = bx * 128;
  const int wr = (wave >> 1) * 64, wc = (wave & 1) * 64;
  // staging: LDS[row][s] holds global[row][s ^ (row&7)] (dest linear, source
  // pre-swizzled; read slot ^ (row&7)).
  const int l8 = lane >> 3, s8 = lane & 7;
  const unsigned short* pA[4];
  const unsigned short* pB[4];
  unsigned short* lA[4];
  unsigned short* lB[4];
#pragma unroll
  for (int r = 0; r < 4; r++) {
    int q = wave * 4 + r;                       // 16 segments x 8 rows = 128 rows
    pA[r] = A + (size_t)(m0 + q * 8 + l8) * K + (s8 ^ l8) * 8;
    pB[r] = Bt + (size_t)(n0 + q * 8 + l8) * K + (s8 ^ l8) * 8;
    lA[r] = &As[q * 512];
    lB[r] = &Bs[q * 512];
  }
  const int fr = lane & 15;
  const int c4 = lane >> 4;
  const int sk0 = (c4 ^ (fr & 7)) * 8;          // kk=0: slots 0..3, swizzled
  const int sk1 = ((4 | c4) ^ (fr & 7)) * 8;    // kk=1: slots 4..7, swizzled
  f32x4 acc[4][4] = {};
  for (int k0 = 0; k0 < K; k0 += 64) {
#pragma unroll
    for (int r = 0; r < 4; r++) {
      gld_lds16(pA[r] + k0, lA[r]);
      gld_lds16(pB[r] + k0, lB[r]);
    }
    asm volatile("s_waitcnt vmcnt(0)" ::: "memory");
    __syncthreads();
    {
      bf16x8 af0[4], bf0[4];
#pragma unroll
      for (int i = 0; i < 4; i++) {
        af0[i] = *(const bf16x8*)&As[(wr + i * 16 + fr) * 64 + sk0];
        bf0[i] = *(const bf16x8*)&Bs[(wc + i * 16 + fr) * 64 + sk0];
      }
#pragma unroll
      for (int i = 0; i < 4; i++)
#pragma unroll
        for (int j = 0; j < 4; j++)
          acc[i][j] = __builtin_amdgcn_mfma_f32_16x16x32_bf16(af0[i], bf0[j], acc[i][j], 0, 0, 0);
    }
    {
      bf16x8 af1[4], bf1[4];
#pragma unroll
      for (int i = 0; i < 4; i++) {
        af1[i] = *(const bf16x8*)&As[(wr + i * 16 + fr) * 64 + sk1];
        bf1[i] = *(const bf16x8*)&Bs[(wc + i * 16 + fr) * 64 + sk1];
      }
#pragma unroll
      for (int i = 0; i < 4; i++)
#pragma unroll
        for (int j = 0; j < 4; j++)
          acc[i][j] = __builtin_amdgcn_mfma_f32_16x16x32_bf16(af1[i], bf1[j], acc[i][j], 0, 0, 0);
    }
    __syncthreads();
  }
  const int crow = (lane >> 4) * 4;
  const int ccol = lane & 15;
#pragma unroll
  for (int i = 0; i < 4; i++) {
#pragma unroll
    for (int j = 0; j < 4; j++) {
      int n = n0 + wc + j * 16 + ccol;
      if (n < N) {
        float c1 = FOLD ? t1[n] : 0.f;
        float c2 = FOLD ? t2[n] : 0.f;
#pragma unroll
        for (int r = 0; r < 4; r++) {
          int m = m0 + wr + i * 16 + crow + r;
          float v = acc[i][j][r];
          if (FOLD) v = rstd[m] * (v - mu[m] * c1) + c2;
          store_out(C, (size_t)m * N + n, v);
        }
      }
    }
  }
}

// ---- K3: causal depthwise conv (k=4) + SiLU, 8 rows x 4 cols per thread.
// bx==0 blocks additionally compute dt = softplus(dt_raw + dt_bias) for
// their 8 rows (256 values over 192 threads).
__global__ void conv_silu_kernel(const unsigned short* __restrict__ zxbcdt,
                                 const float* __restrict__ conv_w,
                                 const float* __restrict__ conv_b,
                                 unsigned short* __restrict__ xbc_act,
                                 const float* __restrict__ dt_bias,
                                 float* __restrict__ dtb) {
  const int r0 = blockIdx.y * 8;
  if (blockIdx.x == 0) {
    for (int e = threadIdx.x; e < 8 * kNH; e += 192) {
      int rr = r0 + (e >> 5), h = e & 31;
      float x = bu2f(zxbcdt[(size_t)rr * kDProj + (kDProj - kNH) + h]) + dt_bias[h];
      dtb[(size_t)rr * kNH + h] = (x > 15.f) ? x : log1pf(expf(x));
    }
  }
  int c4 = blockIdx.x * 192 + threadIdx.x;
  if (c4 >= kConvDim / 4) return;
  const int c = c4 * 4;
  const int l0 = r0 & (kL - 1);
  float4 w[4];
  float bias[4];
#pragma unroll
  for (int q = 0; q < 4; q++) {
    w[q] = ((const float4*)conv_w)[c + q];
    bias[q] = conv_b[c + q];
  }
  float v[11][4];
#pragma unroll
  for (int i = 0; i < 11; i++) {
    int l = l0 - 3 + i;
    if (l >= 0) {
      ushort4 t = *(const ushort4*)&zxbcdt[(size_t)(r0 - 3 + i) * kDProj + kDI + c];
      v[i][0] = bu2f(t.x); v[i][1] = bu2f(t.y); v[i][2] = bu2f(t.z); v[i][3] = bu2f(t.w);
    } else {
      v[i][0] = v[i][1] = v[i][2] = v[i][3] = 0.f;
    }
  }
#pragma unroll
  for (int j = 0; j < 8; j++) {
    ushort4 o;
    unsigned short* op = (unsigned short*)&o;
#pragma unroll
    for (int q = 0; q < 4; q++) {
      float a = bias[q] + v[j][q] * w[q].x + v[j + 1][q] * w[q].y +
                v[j + 2][q] * w[q].z + v[j + 3][q] * w[q].w;
      op[q] = f2bu(a / (1.f + expf(-a)));
    }
    *(ushort4*)&xbc_act[(size_t)(r0 + j) * kConvDim + c] = o;
  }
}

// ---- K4: per-(b,chunk,head) end-of-chunk state via MFMA
__global__ __launch_bounds__(256) void chunk_state_kernel(
    const unsigned short* __restrict__ xbc_act,
    const float* __restrict__ dtbuf,
    const float* __restrict__ A_log,
    unsigned short* __restrict__ states,
    float* __restrict__ asum) {
  const int id = blockIdx.x;
  const int h = id & 31;
  const int c = (id >> 5) & (kNC - 1);
  const int b = id >> 11;
  const int tid = threadIdx.x;
  const int wave = tid >> 6, lane = tid & 63;
  __shared__ __align__(16) unsigned short sBT[kDS * kWS];
  __shared__ __align__(16) unsigned short sxd[kCS * kWS];
  __shared__ float s_dt[kCS];
  __shared__ float s_acum[kCS];
  const int l0 = b * kL + c * kCS;
  if (tid < kCS) s_dt[tid] = dtbuf[(size_t)(l0 + tid) * kNH + h];
  __syncthreads();
  if (tid < 64) {                      // wave-parallel inclusive scan
    float A = -expf(A_log[h]);
    float v = A * s_dt[tid];
#pragma unroll
    for (int off = 1; off < 64; off <<= 1) {
      float u = __shfl_up(v, off);
      if (tid >= off) v += u;
    }
    s_acum[tid] = v;
    if (tid == 63) asum[id] = v;
  }
  __syncthreads();
  const float total = s_acum[kCS - 1];
  for (int e = tid; e < kCS * kDS; e += 256) {
    int s = e >> 7, n = e & 127;
    sBT[n * kWS + s] = xbc_act[(size_t)(l0 + s) * kConvDim + kDI + n];
  }
  for (int e = tid; e < kCS * kHP; e += 256) {
    int s = e >> 6, p = e & 63;
    float xv = bu2f(xbc_act[(size_t)(l0 + s) * kConvDim + h * kHP + p]);
    sxd[p * kWS + s] = f2bu(xv * s_dt[s] * expf(total - s_acum[s]));
  }
  __syncthreads();
  const int arow = wave * 16 + (lane & 15);
  const int fk = (lane >> 4) * 8;
  f32x4 acc[8] = {};
#pragma unroll
  for (int kk = 0; kk < 2; kk++) {
    bf16x8 a = *(const bf16x8*)&sxd[arow * kWS + kk * 32 + fk];
#pragma unroll
    for (int j = 0; j < 8; j++) {
      bf16x8 bb = *(const bf16x8*)&sBT[(j * 16 + (lane & 15)) * kWS + kk * 32 + fk];
      acc[j] = __builtin_amdgcn_mfma_f32_16x16x32_bf16(a, bb, acc[j], 0, 0, 0);
    }
  }
  const int prow = wave * 16 + (lane >> 4) * 4;
  const int ncol = lane & 15;
  size_t base = (size_t)id * (kHP * kDS);
#pragma unroll
  for (int j = 0; j < 8; j++)
#pragma unroll
    for (int r = 0; r < 4; r++)
      states[base + (size_t)(prow + r) * kDS + j * 16 + ncol] = f2bu(acc[j][r]);
}

// ---- K5: sequential inter-chunk scan, ushort2 elements, prefetch depth 2
__global__ void scan_kernel(unsigned short* __restrict__ states,
                            const float* __restrict__ asum) {
  const int blk = blockIdx.x;
  const int seg = blk & 15;
  const int bh = blk >> 4;
  const int h = bh & 31, b = bh >> 5;
  const int e2 = seg * 256 + threadIdx.x;               // ushort2 index, 4096/(b,h)
  const size_t cstride = (size_t)kNH * 4096;            // ushort2 units per chunk
  ushort2* p = (ushort2*)states + ((size_t)(b * kNC) * kNH + h) * 4096 + e2;
  const float* ap = asum + (b * kNC) * kNH + h;
  float c0 = 0.f, c1 = 0.f;
  ushort2 t = p[0];
  float dec = expf(ap[0]);
  ushort2 t1v = p[cstride];                             // kNC >= 2 always
  float dec1 = expf(ap[kNH]);
  for (int c = 0; c < kNC; c++) {
    ushort2 t2v = t1v;
    float dec2 = dec1;
    if (c + 2 < kNC) {                                  // prefetch chunk c+2
      t2v = p[(size_t)(c + 2) * cstride];
      dec2 = expf(ap[(c + 2) * kNH]);
    }
    ushort2 o;
    o.x = f2bu(c0); o.y = f2bu(c1);
    p[(size_t)c * cstride] = o;
    c0 = c0 * dec + bu2f(t.x);
    c1 = c1 * dec + bu2f(t.y);
    t = t1v; dec = dec1;
    t1v = t2v; dec1 = dec2;
  }
}

// ---- K6: intra-chunk Y, 4 heads/block
__global__ __launch_bounds__(256) void y_kernel(
    const unsigned short* __restrict__ xbc_act,
    const unsigned short* __restrict__ zxbcdt,
    const unsigned short* __restrict__ states_in,
    const float* __restrict__ dtbuf,
    const float* __restrict__ A_log,
    unsigned short* __restrict__ ybuf,
    float* __restrict__ pS, float* __restrict__ pQ) {
  const int id = blockIdx.x;                 // (b*NC + c)*8 + hg
  const int hg = id & 7;
  const int c = (id >> 3) & (kNC - 1);
  const int b = id >> 9;
  const int tid = threadIdx.x;
  const int wave = tid >> 6, lane = tid & 63;
  __shared__ __align__(16) unsigned short sC[kCS * kTS];
  __shared__ __align__(16) unsigned short sB[kCS * kTS];
  __shared__ __align__(16) unsigned short sxd[kCS * kWS];
  __shared__ __align__(16) unsigned short sW[kCS * kWS];
  __shared__ float s_dt[4][kCS];
  __shared__ float s_acum[4][kCS];
  const int l0 = b * kL + c * kCS;
  {
    int hh = tid >> 6, s = tid & 63;
    s_dt[hh][s] = dtbuf[(size_t)(l0 + s) * kNH + hg * 4 + hh];
  }
  __syncthreads();
  {                                          // wave-parallel scan, one head/wave
    int hh = tid >> 6, s = tid & 63;
    float A = -expf(A_log[hg * 4 + hh]);
    float v = A * s_dt[hh][s];
#pragma unroll
    for (int off = 1; off < 64; off <<= 1) {
      float u = __shfl_up(v, off);
      if (s >= off) v += u;
    }
    s_acum[hh][s] = v;
  }
  for (int e = tid; e < kCS * 16; e += 256) {
    int row = e >> 4, c8 = (e & 15) * 8;
    size_t rb = (size_t)(l0 + row) * kConvDim;
    *(ushort8*)&sB[row * kTS + c8] = *(const ushort8*)&xbc_act[rb + kDI + c8];
    *(ushort8*)&sC[row * kTS + c8] = *(const ushort8*)&xbc_act[rb + kDI + kDS + c8];
  }
  __syncthreads();
  const int arow = wave * 16 + (lane & 15);
  const int fk = (lane >> 4) * 8;
  // G[l][s] = C . B^T  (K=128) — head-independent, once per block
  f32x4 accG[4] = {};
#pragma unroll
  for (int kk = 0; kk < 4; kk++) {
    bf16x8 a = *(const bf16x8*)&sC[arow * kTS + kk * 32 + fk];
#pragma unroll
    for (int j = 0; j < 4; j++) {
      bf16x8 bb = *(const bf16x8*)&sB[(j * 16 + (lane & 15)) * kTS + kk * 32 + fk];
      accG[j] = __builtin_amdgcn_mfma_f32_16x16x32_bf16(a, bb, accG[j], 0, 0, 0);
    }
  }
  const int lrow = wave * 16 + (lane >> 4) * 4;
  const size_t sbase = (size_t)((b * kNC + c) * kNH) * (kHP * kDS);
  float rS[4] = {}, rQ[4] = {};
  for (int hh = 0; hh < 4; hh++) {
    const int h = hg * 4 + hh;
    __syncthreads();   // prior iteration (or G) done reading sB/sxd/sW
    // stage xd^T for this head
    for (int e = tid; e < kCS * kHP; e += 256) {
      int s = e >> 6, p = e & 63;
      float xv = bu2f(xbc_act[(size_t)(l0 + s) * kConvDim + h * kHP + p]);
      sxd[p * kWS + s] = f2bu(xv * s_dt[hh][s]);
    }
    // W = mask(G)*decay  (wave-local strip)
#pragma unroll
    for (int j = 0; j < 4; j++) {
      int scol = j * 16 + (lane & 15);
      float as = s_acum[hh][scol];
#pragma unroll
      for (int r = 0; r < 4; r++) {
        int l = lrow + r;
        float w = (scol <= l) ? accG[j][r] * expf(s_acum[hh][l] - as) : 0.f;
        sW[l * kWS + scol] = f2bu(w);
      }
    }
    // stage Sin[p][n] for this head into sB
    for (int e = tid; e < kCS * 16; e += 256) {
      int row = e >> 4, c8 = (e & 15) * 8;
      *(ushort8*)&sB[row * kTS + c8] =
          *(const ushort8*)&states_in[sbase + (size_t)h * (kHP * kDS) + row * kDS + c8];
    }
    __syncthreads();
    // Yd = W . xd^T  (K=64)
    f32x4 accY[4] = {};
#pragma unroll
    for (int kk = 0; kk < 2; kk++) {
      bf16x8 a = *(const bf16x8*)&sW[arow * kWS + kk * 32 + fk];
#pragma unroll
      for (int j = 0; j < 4; j++) {
        bf16x8 bb = *(const bf16x8*)&sxd[(j * 16 + (lane & 15)) * kWS + kk * 32 + fk];
        accY[j] = __builtin_amdgcn_mfma_f32_16x16x32_bf16(a, bb, accY[j], 0, 0, 0);
      }
    }
    // Yoff = C . Sin^T  (K=128)
    f32x4 accO[4] = {};
#pragma unroll
    for (int kk = 0; kk < 4; kk++) {
      bf16x8 a = *(const bf16x8*)&sC[arow * kTS + kk * 32 + fk];
#pragma unroll
      for (int j = 0; j < 4; j++) {
        bf16x8 bb = *(const bf16x8*)&sB[(j * 16 + (lane & 15)) * kTS + kk * 32 + fk];
        accO[j] = __builtin_amdgcn_mfma_f32_16x16x32_bf16(a, bb, accO[j], 0, 0, 0);
      }
    }
#pragma unroll
    for (int r = 0; r < 4; r++) {
      int l = lrow + r;
      float el = expf(s_acum[hh][l]);
      size_t zrow = (size_t)(l0 + l) * kDProj + h * kHP;
      size_t yrow = (size_t)(l0 + l) * kDI + h * kHP;
#pragma unroll
      for (int j = 0; j < 4; j++) {
        int p = j * 16 + (lane & 15);
        float yv = accY[j][r] + el * accO[j][r];
        float z = bu2f(zxbcdt[zrow + p]);
        yv *= z / (1.f + expf(-z));
        rS[r] += yv;
        rQ[r] += yv * yv;
        ybuf[yrow + p] = f2bu(yv);
      }
    }
  }
#pragma unroll
  for (int m = 1; m < 16; m <<= 1) {
#pragma unroll
    for (int r = 0; r < 4; r++) {
      rS[r] += __shfl_xor(rS[r], m);
      rQ[r] += __shfl_xor(rQ[r], m);
    }
  }
  if ((lane & 15) == 0) {
#pragma unroll
    for (int r = 0; r < 4; r++) {
      int row = l0 + lrow + r;
      pS[(size_t)row * 8 + hg] = rS[r];
      pQ[(size_t)row * 8 + hg] = rQ[r];
    }
  }
}

// ---- K7: finalize LN stats from per-block partials
__global__ void ln_reduce(const float* __restrict__ pS, const float* __restrict__ pQ,
                          float* __restrict__ mu, float* __restrict__ rstd) {
  int row = blockIdx.x * 256 + threadIdx.x;
  if (row >= kRows) return;
  float s = 0.f, q = 0.f;
#pragma unroll
  for (int i = 0; i < 8; i++) { s += pS[(size_t)row * 8 + i]; q += pQ[(size_t)row * 8 + i]; }
  float m = s / kDI;
  mu[row] = m;
  rstd[row] = rsqrtf(q / kDI - m * m + kEps);
}

}  // namespace

extern "C" void kernel_launch(void* const* d_in, const int* in_sizes, int n_in,
                              void* d_out, int out_size, void* d_ws, size_t ws_size,
                              hipStream_t stream) {
  const float* u       = (const float*)d_in[0];
  const float* W_in    = (const float*)d_in[1];
  const float* conv_w  = (const float*)d_in[2];
  const float* conv_b  = (const float*)d_in[3];
  const float* dt_bias = (const float*)d_in[4];
  const float* A_log   = (const float*)d_in[5];
  const float* norm_w  = (const float*)d_in[6];
  const float* norm_b  = (const float*)d_in[7];
  const float* W_out   = (const float*)d_in[8];
  float* out = (float*)d_out;

  char* ws = (char*)d_ws;
  size_t off = 0;
  auto alloc = [&](size_t bytes) {
    void* p = ws + off;
    off += (bytes + 255) & ~(size_t)255;
    return p;
  };
  unsigned short* zxbcdt = (unsigned short*)alloc((size_t)kRows * kDProj * 2);        // 71.8 MB
  unsigned short* xbc    = (unsigned short*)alloc((size_t)kRows * kConvDim * 2);      // 37.7 MB
  float* dtb             = (float*)alloc((size_t)kRows * kNH * 4);                    //  1.0 MB
  float* asum            = (float*)alloc((size_t)kB * kNC * kNH * 4);                 // 16 KB
  unsigned short* A1     = (unsigned short*)alloc((size_t)kRows * 1024 * 2);          // 16.8 MB
  unsigned short* Bt1    = (unsigned short*)alloc((size_t)kDProjP * 1024 * 2);        //  9.2 MB
  unsigned short* states = (unsigned short*)alloc((size_t)kB * kNC * kNH * kHP * kDS * 2); // 67.1 MB
  unsigned short* Bt2    = (unsigned short*)alloc((size_t)1024 * kDI * 2);            //  4.2 MB
  unsigned short* ybuf   = (unsigned short*)alloc((size_t)kRows * kDI * 2);           // 33.6 MB
  float* mu              = (float*)alloc((size_t)kRows * 4);
  float* rstd            = (float*)alloc((size_t)kRows * 4);
  float* t1              = (float*)alloc(1024 * 4);
  float* t2              = (float*)alloc(1024 * 4);
  float* pS              = (float*)alloc((size_t)kRows * 8 * 4);                      // 256 KB
  float* pQ              = (float*)alloc((size_t)kRows * 8 * 4);                      // 256 KB
  (void)ws_size; (void)in_sizes; (void)n_in; (void)out_size;

  cast_kernel<<<(kRows * 1024 / 4 + 255) / 256, 256, 0, stream>>>(
      (const float4*)u, (ushort4*)A1, kRows * 1024 / 4);
  transpose_cast<<<dim3(kDProjP / 32, 1024 / 32), 256, 0, stream>>>(
      W_in, Bt1, 1024, kDProj, nullptr);
  transpose_cast<<<dim3(1024 / 32, 2048 / 32), 256, 0, stream>>>(
      W_out, Bt2, 2048, 1024, norm_w);
  colsum_kernel<<<16, 256, 0, stream>>>(W_out, norm_w, norm_b, t1, t2);
  gemm_bt<unsigned short, false><<<dim3(kDProjP / 128, kRows / 128), 256, 0, stream>>>(
      A1, Bt1, zxbcdt, kRows, kDProj, 1024, nullptr, nullptr, nullptr, nullptr);
  conv_silu_kernel<<<dim3(3, kRows / 8), 192, 0, stream>>>(zxbcdt, conv_w, conv_b, xbc,
                                                           dt_bias, dtb);
  chunk_state_kernel<<<kB * kNC * kNH, 256, 0, stream>>>(xbc, dtb, A_log, states, asum);
  scan_kernel<<<kB * kNH * 16, 256, 0, stream>>>(states, asum);
  y_kernel<<<kB * kNC * 8, 256, 0, stream>>>(xbc, zxbcdt, states, dtb, A_log, ybuf, pS, pQ);
  ln_reduce<<<kRows / 256, 256, 0, stream>>>(pS, pQ, mu, rstd);
  gemm_bt<float, true><<<dim3(1024 / 128, kRows / 128), 256, 0, stream>>>(
      ybuf, Bt2, out, kRows, 1024, 2048, mu, rstd, t1, t2);
}

// Round 7
// 412.923 us; speedup vs baseline: 1.0687x; 1.0140x over previous
//
#include <hip/hip_runtime.h>
#include <hip/hip_bf16.h>
#include <math.h>

// ---------------------------------------------------------------------------
// Mamba2 forward, MI355X. Round 16: dispatch-graph compaction.
//   - prep_kernel: cast + transpose(W_in) + transpose(W_out) + colsum merged
//     into one dispatch (independent memory-bound work overlaps; 3 fewer
//     launch boundaries).
//   - ln_reduce folded into gemm_fold (per-block mu/rstd from pS/pQ in LDS).
//   - gemm_bt split into named gemm_in / gemm_fold for rocprof visibility.
// GEMM main loops, conv_silu(+dt), chunk_state, scan, y_kernel identical to
// round 15 (418.7us).
// ---------------------------------------------------------------------------

namespace {

constexpr int kB   = 2;
constexpr int kL   = 4096;
constexpr int kDI  = 2048;
constexpr int kDS  = 128;
constexpr int kNH  = 32;
constexpr int kHP  = 64;
constexpr int kDC  = 4;
constexpr int kCS  = 64;
constexpr int kNC  = kL / kCS;
constexpr int kDProj   = 2 * kDI + 2 * kDS + kNH;  // 4384
constexpr int kDProjP  = 4480;                     // 35*128
constexpr int kConvDim = kDI + 2 * kDS;            // 2304
constexpr int kRows = kB * kL;                     // 8192
constexpr float kEps = 1e-5f;
constexpr int kTS = 130;   // LDS stride for [64][128] tiles (bank +1/row)
constexpr int kWS = 68;    // LDS stride for [64][64] tiles  (bank +2/row)

typedef __bf16 bf16x8 __attribute__((ext_vector_type(8)));
typedef float f32x4 __attribute__((ext_vector_type(4)));
typedef unsigned short ushort8 __attribute__((ext_vector_type(8)));

__device__ inline float bu2f(unsigned short u) {
  union { unsigned int i; float f; } x; x.i = ((unsigned int)u) << 16; return x.f;
}
__device__ inline unsigned short f2bu(float f) {
  __hip_bfloat16 h = __float2bfloat16(f);
  return *reinterpret_cast<unsigned short*>(&h);
}

__device__ inline void gld_lds16(const unsigned short* g, unsigned short* l) {
  __builtin_amdgcn_global_load_lds(
      (const __attribute__((address_space(1))) unsigned int*)g,
      (__attribute__((address_space(3))) unsigned int*)l, 16, 0, 0);
}

// ---- P0: fused preprocessing — cast | transpose W_in | transpose W_out | colsum
__global__ void prep_kernel(const float4* __restrict__ u4, ushort4* __restrict__ A1,
                            const float* __restrict__ W_in, unsigned short* __restrict__ Bt1,
                            const float* __restrict__ W_out, unsigned short* __restrict__ Bt2,
                            const float* __restrict__ norm_w, const float* __restrict__ norm_b,
                            float* __restrict__ t1, float* __restrict__ t2) {
  constexpr int kCastBlocks = kRows * 1024 / 4 / 256;          // 8192
  constexpr int kT1X = kDProjP / 32;                           // 140
  constexpr int kT1Blocks = kT1X * (1024 / 32);                // 4480
  constexpr int kT2X = 1024 / 32;                              // 32
  constexpr int kT2Blocks = kT2X * (2048 / 32);                // 2048
  __shared__ float t[32][33];
  __shared__ float p1[4][64], p2[4][64];
  int bid = (int)blockIdx.x;
  const int tid = threadIdx.x;
  if (bid < kCastBlocks) {                       // ---- cast u -> bf16
    int i = bid * 256 + tid;
    float4 v = u4[i];
    ushort4 o;
    o.x = f2bu(v.x); o.y = f2bu(v.y); o.z = f2bu(v.z); o.w = f2bu(v.w);
    A1[i] = o;
    return;
  }
  bid -= kCastBlocks;
  if (bid < kT1Blocks + kT2Blocks) {             // ---- transpose (+scale) casts
    const float* in;
    unsigned short* out;
    int R, C, bx, by;
    const float* scale;
    if (bid < kT1Blocks) {
      in = W_in; out = Bt1; R = 1024; C = kDProj; scale = nullptr;
      bx = bid % kT1X; by = bid / kT1X;
    } else {
      int r = bid - kT1Blocks;
      in = W_out; out = Bt2; R = 2048; C = 1024; scale = norm_w;
      bx = r % kT2X; by = r / kT2X;
    }
    const int c0 = bx * 32, r0 = by * 32;
    const int tx = tid & 31, ty = tid >> 5;
    for (int rr = ty; rr < 32; rr += 8) {
      int c = c0 + tx;
      float v = (c < C) ? in[(size_t)(r0 + rr) * C + c] : 0.f;
      if (scale) v *= scale[r0 + rr];
      t[rr][tx] = v;
    }
    __syncthreads();
    for (int cc = ty; cc < 32; cc += 8) {
      int orow = c0 + cc;
      out[(size_t)orow * R + r0 + tx] = f2bu(t[tx][cc]);
    }
    return;
  }
  bid -= kT1Blocks + kT2Blocks;                  // ---- colsum (16 blocks)
  {
    const int nl = tid & 63;
    const int ks = tid >> 6;
    const int n = bid * 64 + nl;
    float s1 = 0.f, s2 = 0.f;
    for (int k = ks * 512; k < ks * 512 + 512; k++) {
      float v = W_out[(size_t)k * 1024 + n];
      s1 += norm_w[k] * v;
      s2 += norm_b[k] * v;
    }
    p1[ks][nl] = s1; p2[ks][nl] = s2;
    __syncthreads();
    if (tid < 64) {
      t1[bid * 64 + tid] = p1[0][tid] + p1[1][tid] + p1[2][tid] + p1[3][tid];
      t2[bid * 64 + tid] = p2[0][tid] + p2[1][tid] + p2[2][tid] + p2[3][tid];
    }
  }
}

// ---- K1: in-proj GEMM, 128x128 tile, BK=64, XOR-swizzled LDS, XCD swizzle.
__global__ __launch_bounds__(256, 4) void gemm_in(const unsigned short* __restrict__ A,
                                                  const unsigned short* __restrict__ Bt,
                                                  unsigned short* __restrict__ C,
                                                  int M, int N, int K) {
  __shared__ __align__(16) unsigned short As[128 * 64];   // 16 KB
  __shared__ __align__(16) unsigned short Bs[128 * 64];   // 16 KB
  const int tid = threadIdx.x;
  const int wave = tid >> 6, lane = tid & 63;
  const int nwg = (int)(gridDim.x * gridDim.y);
  const int orig = (int)(blockIdx.y * gridDim.x + blockIdx.x);
  const int swz = (orig & 7) * (nwg >> 3) + (orig >> 3);
  const int bx = swz % (int)gridDim.x, by = swz / (int)gridDim.x;
  const int m0 = by * 128, n0 = bx * 128;
  const int wr = (wave >> 1) * 64, wc = (wave & 1) * 64;
  const int l8 = lane >> 3, s8 = lane & 7;
  const unsigned short* pA[4];
  const unsigned short* pB[4];
  unsigned short* lA[4];
  unsigned short* lB[4];
#pragma unroll
  for (int r = 0; r < 4; r++) {
    int q = wave * 4 + r;
    pA[r] = A + (size_t)(m0 + q * 8 + l8) * K + (s8 ^ l8) * 8;
    pB[r] = Bt + (size_t)(n0 + q * 8 + l8) * K + (s8 ^ l8) * 8;
    lA[r] = &As[q * 512];
    lB[r] = &Bs[q * 512];
  }
  const int fr = lane & 15;
  const int c4 = lane >> 4;
  const int sk0 = (c4 ^ (fr & 7)) * 8;
  const int sk1 = ((4 | c4) ^ (fr & 7)) * 8;
  f32x4 acc[4][4] = {};
  for (int k0 = 0; k0 < K; k0 += 64) {
#pragma unroll
    for (int r = 0; r < 4; r++) {
      gld_lds16(pA[r] + k0, lA[r]);
      gld_lds16(pB[r] + k0, lB[r]);
    }
    asm volatile("s_waitcnt vmcnt(0)" ::: "memory");
    __syncthreads();
    {
      bf16x8 af0[4], bf0[4];
#pragma unroll
      for (int i = 0; i < 4; i++) {
        af0[i] = *(const bf16x8*)&As[(wr + i * 16 + fr) * 64 + sk0];
        bf0[i] = *(const bf16x8*)&Bs[(wc + i * 16 + fr) * 64 + sk0];
      }
#pragma unroll
      for (int i = 0; i < 4; i++)
#pragma unroll
        for (int j = 0; j < 4; j++)
          acc[i][j] = __builtin_amdgcn_mfma_f32_16x16x32_bf16(af0[i], bf0[j], acc[i][j], 0, 0, 0);
    }
    {
      bf16x8 af1[4], bf1[4];
#pragma unroll
      for (int i = 0; i < 4; i++) {
        af1[i] = *(const bf16x8*)&As[(wr + i * 16 + fr) * 64 + sk1];
        bf1[i] = *(const bf16x8*)&Bs[(wc + i * 16 + fr) * 64 + sk1];
      }
#pragma unroll
      for (int i = 0; i < 4; i++)
#pragma unroll
        for (int j = 0; j < 4; j++)
          acc[i][j] = __builtin_amdgcn_mfma_f32_16x16x32_bf16(af1[i], bf1[j], acc[i][j], 0, 0, 0);
    }
    __syncthreads();
  }
  const int crow = (lane >> 4) * 4;
  const int ccol = lane & 15;
#pragma unroll
  for (int i = 0; i < 4; i++) {
#pragma unroll
    for (int j = 0; j < 4; j++) {
      int n = n0 + wc + j * 16 + ccol;
      if (n < N) {
#pragma unroll
        for (int r = 0; r < 4; r++) {
          int m = m0 + wr + i * 16 + crow + r;
          C[(size_t)m * N + n] = f2bu(acc[i][j][r]);
        }
      }
    }
  }
}

// ---- K8: output GEMM with fused LayerNorm; mu/rstd computed per-block from
// pS/pQ partials (replaces ln_reduce dispatch).
__global__ __launch_bounds__(256, 4) void gemm_fold(const unsigned short* __restrict__ A,
                                                    const unsigned short* __restrict__ Bt,
                                                    float* __restrict__ C, int M, int N, int K,
                                                    const float* __restrict__ pS,
                                                    const float* __restrict__ pQ,
                                                    const float* __restrict__ t1,
                                                    const float* __restrict__ t2) {
  __shared__ __align__(16) unsigned short As[128 * 64];
  __shared__ __align__(16) unsigned short Bs[128 * 64];
  __shared__ float smu[128], srstd[128];
  const int tid = threadIdx.x;
  const int wave = tid >> 6, lane = tid & 63;
  const int nwg = (int)(gridDim.x * gridDim.y);
  const int orig = (int)(blockIdx.y * gridDim.x + blockIdx.x);
  const int swz = (orig & 7) * (nwg >> 3) + (orig >> 3);
  const int bx = swz % (int)gridDim.x, by = swz / (int)gridDim.x;
  const int m0 = by * 128, n0 = bx * 128;
  if (tid < 128) {                     // LN stats for this block's 128 rows
    int row = m0 + tid;
    float s = 0.f, q = 0.f;
#pragma unroll
    for (int i = 0; i < 8; i++) { s += pS[(size_t)row * 8 + i]; q += pQ[(size_t)row * 8 + i]; }
    float mval = s / kDI;
    smu[tid] = mval;
    srstd[tid] = rsqrtf(q / kDI - mval * mval + kEps);
  }
  const int wr = (wave >> 1) * 64, wc = (wave & 1) * 64;
  const int l8 = lane >> 3, s8 = lane & 7;
  const unsigned short* pA[4];
  const unsigned short* pB[4];
  unsigned short* lA[4];
  unsigned short* lB[4];
#pragma unroll
  for (int r = 0; r < 4; r++) {
    int q = wave * 4 + r;
    pA[r] = A + (size_t)(m0 + q * 8 + l8) * K + (s8 ^ l8) * 8;
    pB[r] = Bt + (size_t)(n0 + q * 8 + l8) * K + (s8 ^ l8) * 8;
    lA[r] = &As[q * 512];
    lB[r] = &Bs[q * 512];
  }
  const int fr = lane & 15;
  const int c4 = lane >> 4;
  const int sk0 = (c4 ^ (fr & 7)) * 8;
  const int sk1 = ((4 | c4) ^ (fr & 7)) * 8;
  f32x4 acc[4][4] = {};
  for (int k0 = 0; k0 < K; k0 += 64) {
#pragma unroll
    for (int r = 0; r < 4; r++) {
      gld_lds16(pA[r] + k0, lA[r]);
      gld_lds16(pB[r] + k0, lB[r]);
    }
    asm volatile("s_waitcnt vmcnt(0)" ::: "memory");
    __syncthreads();
    {
      bf16x8 af0[4], bf0[4];
#pragma unroll
      for (int i = 0; i < 4; i++) {
        af0[i] = *(const bf16x8*)&As[(wr + i * 16 + fr) * 64 + sk0];
        bf0[i] = *(const bf16x8*)&Bs[(wc + i * 16 + fr) * 64 + sk0];
      }
#pragma unroll
      for (int i = 0; i < 4; i++)
#pragma unroll
        for (int j = 0; j < 4; j++)
          acc[i][j] = __builtin_amdgcn_mfma_f32_16x16x32_bf16(af0[i], bf0[j], acc[i][j], 0, 0, 0);
    }
    {
      bf16x8 af1[4], bf1[4];
#pragma unroll
      for (int i = 0; i < 4; i++) {
        af1[i] = *(const bf16x8*)&As[(wr + i * 16 + fr) * 64 + sk1];
        bf1[i] = *(const bf16x8*)&Bs[(wc + i * 16 + fr) * 64 + sk1];
      }
#pragma unroll
      for (int i = 0; i < 4; i++)
#pragma unroll
        for (int j = 0; j < 4; j++)
          acc[i][j] = __builtin_amdgcn_mfma_f32_16x16x32_bf16(af1[i], bf1[j], acc[i][j], 0, 0, 0);
    }
    __syncthreads();
  }
  const int crow = (lane >> 4) * 4;
  const int ccol = lane & 15;
#pragma unroll
  for (int i = 0; i < 4; i++) {
#pragma unroll
    for (int j = 0; j < 4; j++) {
      int n = n0 + wc + j * 16 + ccol;
      float c1 = t1[n];
      float c2 = t2[n];
#pragma unroll
      for (int r = 0; r < 4; r++) {
        int ml = wr + i * 16 + crow + r;
        float v = acc[i][j][r];
        v = srstd[ml] * (v - smu[ml] * c1) + c2;
        C[(size_t)(m0 + ml) * N + n] = v;
      }
    }
  }
}

// ---- K3: causal depthwise conv (k=4) + SiLU; bx==0 also computes dt softplus
__global__ void conv_silu_kernel(const unsigned short* __restrict__ zxbcdt,
                                 const float* __restrict__ conv_w,
                                 const float* __restrict__ conv_b,
                                 unsigned short* __restrict__ xbc_act,
                                 const float* __restrict__ dt_bias,
                                 float* __restrict__ dtb) {
  const int r0 = blockIdx.y * 8;
  if (blockIdx.x == 0) {
    for (int e = threadIdx.x; e < 8 * kNH; e += 192) {
      int rr = r0 + (e >> 5), h = e & 31;
      float x = bu2f(zxbcdt[(size_t)rr * kDProj + (kDProj - kNH) + h]) + dt_bias[h];
      dtb[(size_t)rr * kNH + h] = (x > 15.f) ? x : log1pf(expf(x));
    }
  }
  int c4 = blockIdx.x * 192 + threadIdx.x;
  if (c4 >= kConvDim / 4) return;
  const int c = c4 * 4;
  const int l0 = r0 & (kL - 1);
  float4 w[4];
  float bias[4];
#pragma unroll
  for (int q = 0; q < 4; q++) {
    w[q] = ((const float4*)conv_w)[c + q];
    bias[q] = conv_b[c + q];
  }
  float v[11][4];
#pragma unroll
  for (int i = 0; i < 11; i++) {
    int l = l0 - 3 + i;
    if (l >= 0) {
      ushort4 t = *(const ushort4*)&zxbcdt[(size_t)(r0 - 3 + i) * kDProj + kDI + c];
      v[i][0] = bu2f(t.x); v[i][1] = bu2f(t.y); v[i][2] = bu2f(t.z); v[i][3] = bu2f(t.w);
    } else {
      v[i][0] = v[i][1] = v[i][2] = v[i][3] = 0.f;
    }
  }
#pragma unroll
  for (int j = 0; j < 8; j++) {
    ushort4 o;
    unsigned short* op = (unsigned short*)&o;
#pragma unroll
    for (int q = 0; q < 4; q++) {
      float a = bias[q] + v[j][q] * w[q].x + v[j + 1][q] * w[q].y +
                v[j + 2][q] * w[q].z + v[j + 3][q] * w[q].w;
      op[q] = f2bu(a / (1.f + expf(-a)));
    }
    *(ushort4*)&xbc_act[(size_t)(r0 + j) * kConvDim + c] = o;
  }
}

// ---- K4: per-(b,chunk,head) end-of-chunk state via MFMA
__global__ __launch_bounds__(256) void chunk_state_kernel(
    const unsigned short* __restrict__ xbc_act,
    const float* __restrict__ dtbuf,
    const float* __restrict__ A_log,
    unsigned short* __restrict__ states,
    float* __restrict__ asum) {
  const int id = blockIdx.x;
  const int h = id & 31;
  const int c = (id >> 5) & (kNC - 1);
  const int b = id >> 11;
  const int tid = threadIdx.x;
  const int wave = tid >> 6, lane = tid & 63;
  __shared__ __align__(16) unsigned short sBT[kDS * kWS];
  __shared__ __align__(16) unsigned short sxd[kCS * kWS];
  __shared__ float s_dt[kCS];
  __shared__ float s_acum[kCS];
  const int l0 = b * kL + c * kCS;
  if (tid < kCS) s_dt[tid] = dtbuf[(size_t)(l0 + tid) * kNH + h];
  __syncthreads();
  if (tid < 64) {                      // wave-parallel inclusive scan
    float A = -expf(A_log[h]);
    float v = A * s_dt[tid];
#pragma unroll
    for (int off = 1; off < 64; off <<= 1) {
      float u = __shfl_up(v, off);
      if (tid >= off) v += u;
    }
    s_acum[tid] = v;
    if (tid == 63) asum[id] = v;
  }
  __syncthreads();
  const float total = s_acum[kCS - 1];
  for (int e = tid; e < kCS * kDS; e += 256) {
    int s = e >> 7, n = e & 127;
    sBT[n * kWS + s] = xbc_act[(size_t)(l0 + s) * kConvDim + kDI + n];
  }
  for (int e = tid; e < kCS * kHP; e += 256) {
    int s = e >> 6, p = e & 63;
    float xv = bu2f(xbc_act[(size_t)(l0 + s) * kConvDim + h * kHP + p]);
    sxd[p * kWS + s] = f2bu(xv * s_dt[s] * expf(total - s_acum[s]));
  }
  __syncthreads();
  const int arow = wave * 16 + (lane & 15);
  const int fk = (lane >> 4) * 8;
  f32x4 acc[8] = {};
#pragma unroll
  for (int kk = 0; kk < 2; kk++) {
    bf16x8 a = *(const bf16x8*)&sxd[arow * kWS + kk * 32 + fk];
#pragma unroll
    for (int j = 0; j < 8; j++) {
      bf16x8 bb = *(const bf16x8*)&sBT[(j * 16 + (lane & 15)) * kWS + kk * 32 + fk];
      acc[j] = __builtin_amdgcn_mfma_f32_16x16x32_bf16(a, bb, acc[j], 0, 0, 0);
    }
  }
  const int prow = wave * 16 + (lane >> 4) * 4;
  const int ncol = lane & 15;
  size_t base = (size_t)id * (kHP * kDS);
#pragma unroll
  for (int j = 0; j < 8; j++)
#pragma unroll
    for (int r = 0; r < 4; r++)
      states[base + (size_t)(prow + r) * kDS + j * 16 + ncol] = f2bu(acc[j][r]);
}

// ---- K5: sequential inter-chunk scan, ushort2 elements, prefetch depth 2
__global__ void scan_kernel(unsigned short* __restrict__ states,
                            const float* __restrict__ asum) {
  const int blk = blockIdx.x;
  const int seg = blk & 15;
  const int bh = blk >> 4;
  const int h = bh & 31, b = bh >> 5;
  const int e2 = seg * 256 + threadIdx.x;               // ushort2 index, 4096/(b,h)
  const size_t cstride = (size_t)kNH * 4096;            // ushort2 units per chunk
  ushort2* p = (ushort2*)states + ((size_t)(b * kNC) * kNH + h) * 4096 + e2;
  const float* ap = asum + (b * kNC) * kNH + h;
  float c0 = 0.f, c1 = 0.f;
  ushort2 t = p[0];
  float dec = expf(ap[0]);
  ushort2 t1v = p[cstride];                             // kNC >= 2 always
  float dec1 = expf(ap[kNH]);
  for (int c = 0; c < kNC; c++) {
    ushort2 t2v = t1v;
    float dec2 = dec1;
    if (c + 2 < kNC) {                                  // prefetch chunk c+2
      t2v = p[(size_t)(c + 2) * cstride];
      dec2 = expf(ap[(c + 2) * kNH]);
    }
    ushort2 o;
    o.x = f2bu(c0); o.y = f2bu(c1);
    p[(size_t)c * cstride] = o;
    c0 = c0 * dec + bu2f(t.x);
    c1 = c1 * dec + bu2f(t.y);
    t = t1v; dec = dec1;
    t1v = t2v; dec1 = dec2;
  }
}

// ---- K6: intra-chunk Y, 4 heads/block
__global__ __launch_bounds__(256) void y_kernel(
    const unsigned short* __restrict__ xbc_act,
    const unsigned short* __restrict__ zxbcdt,
    const unsigned short* __restrict__ states_in,
    const float* __restrict__ dtbuf,
    const float* __restrict__ A_log,
    unsigned short* __restrict__ ybuf,
    float* __restrict__ pS, float* __restrict__ pQ) {
  const int id = blockIdx.x;                 // (b*NC + c)*8 + hg
  const int hg = id & 7;
  const int c = (id >> 3) & (kNC - 1);
  const int b = id >> 9;
  const int tid = threadIdx.x;
  const int wave = tid >> 6, lane = tid & 63;
  __shared__ __align__(16) unsigned short sC[kCS * kTS];
  __shared__ __align__(16) unsigned short sB[kCS * kTS];
  __shared__ __align__(16) unsigned short sxd[kCS * kWS];
  __shared__ __align__(16) unsigned short sW[kCS * kWS];
  __shared__ float s_dt[4][kCS];
  __shared__ float s_acum[4][kCS];
  const int l0 = b * kL + c * kCS;
  {
    int hh = tid >> 6, s = tid & 63;
    s_dt[hh][s] = dtbuf[(size_t)(l0 + s) * kNH + hg * 4 + hh];
  }
  __syncthreads();
  {                                          // wave-parallel scan, one head/wave
    int hh = tid >> 6, s = tid & 63;
    float A = -expf(A_log[hg * 4 + hh]);
    float v = A * s_dt[hh][s];
#pragma unroll
    for (int off = 1; off < 64; off <<= 1) {
      float u = __shfl_up(v, off);
      if (s >= off) v += u;
    }
    s_acum[hh][s] = v;
  }
  for (int e = tid; e < kCS * 16; e += 256) {
    int row = e >> 4, c8 = (e & 15) * 8;
    size_t rb = (size_t)(l0 + row) * kConvDim;
    *(ushort8*)&sB[row * kTS + c8] = *(const ushort8*)&xbc_act[rb + kDI + c8];
    *(ushort8*)&sC[row * kTS + c8] = *(const ushort8*)&xbc_act[rb + kDI + kDS + c8];
  }
  __syncthreads();
  const int arow = wave * 16 + (lane & 15);
  const int fk = (lane >> 4) * 8;
  // G[l][s] = C . B^T  (K=128) — head-independent, once per block
  f32x4 accG[4] = {};
#pragma unroll
  for (int kk = 0; kk < 4; kk++) {
    bf16x8 a = *(const bf16x8*)&sC[arow * kTS + kk * 32 + fk];
#pragma unroll
    for (int j = 0; j < 4; j++) {
      bf16x8 bb = *(const bf16x8*)&sB[(j * 16 + (lane & 15)) * kTS + kk * 32 + fk];
      accG[j] = __builtin_amdgcn_mfma_f32_16x16x32_bf16(a, bb, accG[j], 0, 0, 0);
    }
  }
  const int lrow = wave * 16 + (lane >> 4) * 4;
  const size_t sbase = (size_t)((b * kNC + c) * kNH) * (kHP * kDS);
  float rS[4] = {}, rQ[4] = {};
  for (int hh = 0; hh < 4; hh++) {
    const int h = hg * 4 + hh;
    __syncthreads();   // prior iteration (or G) done reading sB/sxd/sW
    // stage xd^T for this head
    for (int e = tid; e < kCS * kHP; e += 256) {
      int s = e >> 6, p = e & 63;
      float xv = bu2f(xbc_act[(size_t)(l0 + s) * kConvDim + h * kHP + p]);
      sxd[p * kWS + s] = f2bu(xv * s_dt[hh][s]);
    }
    // W = mask(G)*decay  (wave-local strip)
#pragma unroll
    for (int j = 0; j < 4; j++) {
      int scol = j * 16 + (lane & 15);
      float as = s_acum[hh][scol];
#pragma unroll
      for (int r = 0; r < 4; r++) {
        int l = lrow + r;
        float w = (scol <= l) ? accG[j][r] * expf(s_acum[hh][l] - as) : 0.f;
        sW[l * kWS + scol] = f2bu(w);
      }
    }
    // stage Sin[p][n] for this head into sB
    for (int e = tid; e < kCS * 16; e += 256) {
      int row = e >> 4, c8 = (e & 15) * 8;
      *(ushort8*)&sB[row * kTS + c8] =
          *(const ushort8*)&states_in[sbase + (size_t)h * (kHP * kDS) + row * kDS + c8];
    }
    __syncthreads();
    // Yd = W . xd^T  (K=64)
    f32x4 accY[4] = {};
#pragma unroll
    for (int kk = 0; kk < 2; kk++) {
      bf16x8 a = *(const bf16x8*)&sW[arow * kWS + kk * 32 + fk];
#pragma unroll
      for (int j = 0; j < 4; j++) {
        bf16x8 bb = *(const bf16x8*)&sxd[(j * 16 + (lane & 15)) * kWS + kk * 32 + fk];
        accY[j] = __builtin_amdgcn_mfma_f32_16x16x32_bf16(a, bb, accY[j], 0, 0, 0);
      }
    }
    // Yoff = C . Sin^T  (K=128)
    f32x4 accO[4] = {};
#pragma unroll
    for (int kk = 0; kk < 4; kk++) {
      bf16x8 a = *(const bf16x8*)&sC[arow * kTS + kk * 32 + fk];
#pragma unroll
      for (int j = 0; j < 4; j++) {
        bf16x8 bb = *(const bf16x8*)&sB[(j * 16 + (lane & 15)) * kTS + kk * 32 + fk];
        accO[j] = __builtin_amdgcn_mfma_f32_16x16x32_bf16(a, bb, accO[j], 0, 0, 0);
      }
    }
#pragma unroll
    for (int r = 0; r < 4; r++) {
      int l = lrow + r;
      float el = expf(s_acum[hh][l]);
      size_t zrow = (size_t)(l0 + l) * kDProj + h * kHP;
      size_t yrow = (size_t)(l0 + l) * kDI + h * kHP;
#pragma unroll
      for (int j = 0; j < 4; j++) {
        int p = j * 16 + (lane & 15);
        float yv = accY[j][r] + el * accO[j][r];
        float z = bu2f(zxbcdt[zrow + p]);
        yv *= z / (1.f + expf(-z));
        rS[r] += yv;
        rQ[r] += yv * yv;
        ybuf[yrow + p] = f2bu(yv);
      }
    }
  }
#pragma unroll
  for (int m = 1; m < 16; m <<= 1) {
#pragma unroll
    for (int r = 0; r < 4; r++) {
      rS[r] += __shfl_xor(rS[r], m);
      rQ[r] += __shfl_xor(rQ[r], m);
    }
  }
  if ((lane & 15) == 0) {
#pragma unroll
    for (int r = 0; r < 4; r++) {
      int row = l0 + lrow + r;
      pS[(size_t)row * 8 + hg] = rS[r];
      pQ[(size_t)row * 8 + hg] = rQ[r];
    }
  }
}

}  // namespace

extern "C" void kernel_launch(void* const* d_in, const int* in_sizes, int n_in,
                              void* d_out, int out_size, void* d_ws, size_t ws_size,
                              hipStream_t stream) {
  const float* u       = (const float*)d_in[0];
  const float* W_in    = (const float*)d_in[1];
  const float* conv_w  = (const float*)d_in[2];
  const float* conv_b  = (const float*)d_in[3];
  const float* dt_bias = (const float*)d_in[4];
  const float* A_log   = (const float*)d_in[5];
  const float* norm_w  = (const float*)d_in[6];
  const float* norm_b  = (const float*)d_in[7];
  const float* W_out   = (const float*)d_in[8];
  float* out = (float*)d_out;

  char* ws = (char*)d_ws;
  size_t off = 0;
  auto alloc = [&](size_t bytes) {
    void* p = ws + off;
    off += (bytes + 255) & ~(size_t)255;
    return p;
  };
  unsigned short* zxbcdt = (unsigned short*)alloc((size_t)kRows * kDProj * 2);        // 71.8 MB
  unsigned short* xbc    = (unsigned short*)alloc((size_t)kRows * kConvDim * 2);      // 37.7 MB
  float* dtb             = (float*)alloc((size_t)kRows * kNH * 4);                    //  1.0 MB
  float* asum            = (float*)alloc((size_t)kB * kNC * kNH * 4);                 // 16 KB
  unsigned short* A1     = (unsigned short*)alloc((size_t)kRows * 1024 * 2);          // 16.8 MB
  unsigned short* Bt1    = (unsigned short*)alloc((size_t)kDProjP * 1024 * 2);        //  9.2 MB
  unsigned short* states = (unsigned short*)alloc((size_t)kB * kNC * kNH * kHP * kDS * 2); // 67.1 MB
  unsigned short* Bt2    = (unsigned short*)alloc((size_t)1024 * kDI * 2);            //  4.2 MB
  unsigned short* ybuf   = (unsigned short*)alloc((size_t)kRows * kDI * 2);           // 33.6 MB
  float* t1              = (float*)alloc(1024 * 4);
  float* t2              = (float*)alloc(1024 * 4);
  float* pS              = (float*)alloc((size_t)kRows * 8 * 4);                      // 256 KB
  float* pQ              = (float*)alloc((size_t)kRows * 8 * 4);                      // 256 KB
  (void)ws_size; (void)in_sizes; (void)n_in; (void)out_size;

  constexpr int kPrepBlocks = kRows * 1024 / 4 / 256                    // 8192
                            + (kDProjP / 32) * (1024 / 32)              // 4480
                            + (1024 / 32) * (2048 / 32)                 // 2048
                            + 16;                                       // 14736
  prep_kernel<<<kPrepBlocks, 256, 0, stream>>>(
      (const float4*)u, (ushort4*)A1, W_in, Bt1, W_out, Bt2, norm_w, norm_b, t1, t2);
  gemm_in<<<dim3(kDProjP / 128, kRows / 128), 256, 0, stream>>>(
      A1, Bt1, zxbcdt, kRows, kDProj, 1024);
  conv_silu_kernel<<<dim3(3, kRows / 8), 192, 0, stream>>>(zxbcdt, conv_w, conv_b, xbc,
                                                           dt_bias, dtb);
  chunk_state_kernel<<<kB * kNC * kNH, 256, 0, stream>>>(xbc, dtb, A_log, states, asum);
  scan_kernel<<<kB * kNH * 16, 256, 0, stream>>>(states, asum);
  y_kernel<<<kB * kNC * 8, 256, 0, stream>>>(xbc, zxbcdt, states, dtb, A_log, ybuf, pS, pQ);
  gemm_fold<<<dim3(1024 / 128, kRows / 128), 256, 0, stream>>>(
      ybuf, Bt2, out, kRows, 1024, 2048, pS, pQ, t1, t2);
}

// Round 10
// 410.828 us; speedup vs baseline: 1.0741x; 1.0051x over previous
//
#include <hip/hip_runtime.h>
#include <hip/hip_bf16.h>
#include <math.h>

// ---------------------------------------------------------------------------
// Mamba2 forward, MI355X. Round 19: two consecutive container failures on the
// round-17 source -> split the basket for attribution. This file = round-16
// verified base (412.9us) + the two SIMPLE round-17 changes:
//   - gemm_fold retiled 128x128 -> 64x128 (grid 512->1024 = 4 blocks/CU).
//   - scan: depth-4 rolling-window prefetch.
// The complex y_kernel register-prefetch (cross-barrier register lifetimes)
// is DROPPED — y_kernel reverts to the round-16 form. If this round also
// fails, the source is exonerated (95% of it ran fine) -> infra.
// ---------------------------------------------------------------------------

namespace {

constexpr int kB   = 2;
constexpr int kL   = 4096;
constexpr int kDI  = 2048;
constexpr int kDS  = 128;
constexpr int kNH  = 32;
constexpr int kHP  = 64;
constexpr int kDC  = 4;
constexpr int kCS  = 64;
constexpr int kNC  = kL / kCS;
constexpr int kDProj   = 2 * kDI + 2 * kDS + kNH;  // 4384
constexpr int kDProjP  = 4480;                     // 35*128
constexpr int kConvDim = kDI + 2 * kDS;            // 2304
constexpr int kRows = kB * kL;                     // 8192
constexpr float kEps = 1e-5f;
constexpr int kTS = 130;   // LDS stride for [64][128] tiles (bank +1/row)
constexpr int kWS = 68;    // LDS stride for [64][64] tiles  (bank +2/row)

typedef __bf16 bf16x8 __attribute__((ext_vector_type(8)));
typedef float f32x4 __attribute__((ext_vector_type(4)));
typedef unsigned short ushort8 __attribute__((ext_vector_type(8)));

__device__ inline float bu2f(unsigned short u) {
  union { unsigned int i; float f; } x; x.i = ((unsigned int)u) << 16; return x.f;
}
__device__ inline unsigned short f2bu(float f) {
  __hip_bfloat16 h = __float2bfloat16(f);
  return *reinterpret_cast<unsigned short*>(&h);
}

__device__ inline void gld_lds16(const unsigned short* g, unsigned short* l) {
  __builtin_amdgcn_global_load_lds(
      (const __attribute__((address_space(1))) unsigned int*)g,
      (__attribute__((address_space(3))) unsigned int*)l, 16, 0, 0);
}

// ---- P0: fused preprocessing — cast | transpose W_in | transpose W_out | colsum
__global__ void prep_kernel(const float4* __restrict__ u4, ushort4* __restrict__ A1,
                            const float* __restrict__ W_in, unsigned short* __restrict__ Bt1,
                            const float* __restrict__ W_out, unsigned short* __restrict__ Bt2,
                            const float* __restrict__ norm_w, const float* __restrict__ norm_b,
                            float* __restrict__ t1, float* __restrict__ t2) {
  constexpr int kCastBlocks = kRows * 1024 / 4 / 256;          // 8192
  constexpr int kT1X = kDProjP / 32;                           // 140
  constexpr int kT1Blocks = kT1X * (1024 / 32);                // 4480
  constexpr int kT2X = 1024 / 32;                              // 32
  constexpr int kT2Blocks = kT2X * (2048 / 32);                // 2048
  __shared__ float t[32][33];
  __shared__ float p1[4][64], p2[4][64];
  int bid = (int)blockIdx.x;
  const int tid = threadIdx.x;
  if (bid < kCastBlocks) {                       // ---- cast u -> bf16
    int i = bid * 256 + tid;
    float4 v = u4[i];
    ushort4 o;
    o.x = f2bu(v.x); o.y = f2bu(v.y); o.z = f2bu(v.z); o.w = f2bu(v.w);
    A1[i] = o;
    return;
  }
  bid -= kCastBlocks;
  if (bid < kT1Blocks + kT2Blocks) {             // ---- transpose (+scale) casts
    const float* in;
    unsigned short* out;
    int R, C, bx, by;
    const float* scale;
    if (bid < kT1Blocks) {
      in = W_in; out = Bt1; R = 1024; C = kDProj; scale = nullptr;
      bx = bid % kT1X; by = bid / kT1X;
    } else {
      int r = bid - kT1Blocks;
      in = W_out; out = Bt2; R = 2048; C = 1024; scale = norm_w;
      bx = r % kT2X; by = r / kT2X;
    }
    const int c0 = bx * 32, r0 = by * 32;
    const int tx = tid & 31, ty = tid >> 5;
    for (int rr = ty; rr < 32; rr += 8) {
      int c = c0 + tx;
      float v = (c < C) ? in[(size_t)(r0 + rr) * C + c] : 0.f;
      if (scale) v *= scale[r0 + rr];
      t[rr][tx] = v;
    }
    __syncthreads();
    for (int cc = ty; cc < 32; cc += 8) {
      int orow = c0 + cc;
      out[(size_t)orow * R + r0 + tx] = f2bu(t[tx][cc]);
    }
    return;
  }
  bid -= kT1Blocks + kT2Blocks;                  // ---- colsum (16 blocks)
  {
    const int nl = tid & 63;
    const int ks = tid >> 6;
    const int n = bid * 64 + nl;
    float s1 = 0.f, s2 = 0.f;
    for (int k = ks * 512; k < ks * 512 + 512; k++) {
      float v = W_out[(size_t)k * 1024 + n];
      s1 += norm_w[k] * v;
      s2 += norm_b[k] * v;
    }
    p1[ks][nl] = s1; p2[ks][nl] = s2;
    __syncthreads();
    if (tid < 64) {
      t1[bid * 64 + tid] = p1[0][tid] + p1[1][tid] + p1[2][tid] + p1[3][tid];
      t2[bid * 64 + tid] = p2[0][tid] + p2[1][tid] + p2[2][tid] + p2[3][tid];
    }
  }
}

// ---- K1: in-proj GEMM, 128x128 tile, BK=64, XOR-swizzled LDS, XCD swizzle.
__global__ __launch_bounds__(256, 4) void gemm_in(const unsigned short* __restrict__ A,
                                                  const unsigned short* __restrict__ Bt,
                                                  unsigned short* __restrict__ C,
                                                  int M, int N, int K) {
  __shared__ __align__(16) unsigned short As[128 * 64];   // 16 KB
  __shared__ __align__(16) unsigned short Bs[128 * 64];   // 16 KB
  const int tid = threadIdx.x;
  const int wave = tid >> 6, lane = tid & 63;
  const int nwg = (int)(gridDim.x * gridDim.y);
  const int orig = (int)(blockIdx.y * gridDim.x + blockIdx.x);
  const int swz = (orig & 7) * (nwg >> 3) + (orig >> 3);
  const int bx = swz % (int)gridDim.x, by = swz / (int)gridDim.x;
  const int m0 = by * 128, n0 = bx * 128;
  const int wr = (wave >> 1) * 64, wc = (wave & 1) * 64;
  const int l8 = lane >> 3, s8 = lane & 7;
  const unsigned short* pA[4];
  const unsigned short* pB[4];
  unsigned short* lA[4];
  unsigned short* lB[4];
#pragma unroll
  for (int r = 0; r < 4; r++) {
    int q = wave * 4 + r;
    pA[r] = A + (size_t)(m0 + q * 8 + l8) * K + (s8 ^ l8) * 8;
    pB[r] = Bt + (size_t)(n0 + q * 8 + l8) * K + (s8 ^ l8) * 8;
    lA[r] = &As[q * 512];
    lB[r] = &Bs[q * 512];
  }
  const int fr = lane & 15;
  const int c4 = lane >> 4;
  const int sk0 = (c4 ^ (fr & 7)) * 8;
  const int sk1 = ((4 | c4) ^ (fr & 7)) * 8;
  f32x4 acc[4][4] = {};
  for (int k0 = 0; k0 < K; k0 += 64) {
#pragma unroll
    for (int r = 0; r < 4; r++) {
      gld_lds16(pA[r] + k0, lA[r]);
      gld_lds16(pB[r] + k0, lB[r]);
    }
    asm volatile("s_waitcnt vmcnt(0)" ::: "memory");
    __syncthreads();
    {
      bf16x8 af0[4], bf0[4];
#pragma unroll
      for (int i = 0; i < 4; i++) {
        af0[i] = *(const bf16x8*)&As[(wr + i * 16 + fr) * 64 + sk0];
        bf0[i] = *(const bf16x8*)&Bs[(wc + i * 16 + fr) * 64 + sk0];
      }
#pragma unroll
      for (int i = 0; i < 4; i++)
#pragma unroll
        for (int j = 0; j < 4; j++)
          acc[i][j] = __builtin_amdgcn_mfma_f32_16x16x32_bf16(af0[i], bf0[j], acc[i][j], 0, 0, 0);
    }
    {
      bf16x8 af1[4], bf1[4];
#pragma unroll
      for (int i = 0; i < 4; i++) {
        af1[i] = *(const bf16x8*)&As[(wr + i * 16 + fr) * 64 + sk1];
        bf1[i] = *(const bf16x8*)&Bs[(wc + i * 16 + fr) * 64 + sk1];
      }
#pragma unroll
      for (int i = 0; i < 4; i++)
#pragma unroll
        for (int j = 0; j < 4; j++)
          acc[i][j] = __builtin_amdgcn_mfma_f32_16x16x32_bf16(af1[i], bf1[j], acc[i][j], 0, 0, 0);
    }
    __syncthreads();
  }
  const int crow = (lane >> 4) * 4;
  const int ccol = lane & 15;
#pragma unroll
  for (int i = 0; i < 4; i++) {
#pragma unroll
    for (int j = 0; j < 4; j++) {
      int n = n0 + wc + j * 16 + ccol;
      if (n < N) {
#pragma unroll
        for (int r = 0; r < 4; r++) {
          int m = m0 + wr + i * 16 + crow + r;
          C[(size_t)m * N + n] = f2bu(acc[i][j][r]);
        }
      }
    }
  }
}

// ---- K8: output GEMM with fused LayerNorm, 64x128 tile (grid 1024 = 4/CU).
__global__ __launch_bounds__(256, 4) void gemm_fold(const unsigned short* __restrict__ A,
                                                    const unsigned short* __restrict__ Bt,
                                                    float* __restrict__ C, int M, int N, int K,
                                                    const float* __restrict__ pS,
                                                    const float* __restrict__ pQ,
                                                    const float* __restrict__ t1,
                                                    const float* __restrict__ t2) {
  __shared__ __align__(16) unsigned short As[64 * 64];    // 8 KB
  __shared__ __align__(16) unsigned short Bs[128 * 64];   // 16 KB
  __shared__ float smu[64], srstd[64];
  const int tid = threadIdx.x;
  const int wave = tid >> 6, lane = tid & 63;
  const int nwg = (int)(gridDim.x * gridDim.y);
  const int orig = (int)(blockIdx.y * gridDim.x + blockIdx.x);
  const int swz = (orig & 7) * (nwg >> 3) + (orig >> 3);
  const int bx = swz % (int)gridDim.x, by = swz / (int)gridDim.x;
  const int m0 = by * 64, n0 = bx * 128;
  if (tid < 64) {                      // LN stats for this block's 64 rows
    int row = m0 + tid;
    float s = 0.f, q = 0.f;
#pragma unroll
    for (int i = 0; i < 8; i++) { s += pS[(size_t)row * 8 + i]; q += pQ[(size_t)row * 8 + i]; }
    float mval = s / kDI;
    smu[tid] = mval;
    srstd[tid] = rsqrtf(q / kDI - mval * mval + kEps);
  }
  const int wr = (wave >> 1) * 32, wc = (wave & 1) * 64;
  const int l8 = lane >> 3, s8 = lane & 7;
  const unsigned short* pA[2];
  const unsigned short* pB[4];
  unsigned short* lA[2];
  unsigned short* lB[4];
#pragma unroll
  for (int r = 0; r < 2; r++) {
    int q = wave * 2 + r;                       // 8 segments x 8 rows = 64 rows
    pA[r] = A + (size_t)(m0 + q * 8 + l8) * K + (s8 ^ l8) * 8;
    lA[r] = &As[q * 512];
  }
#pragma unroll
  for (int r = 0; r < 4; r++) {
    int q = wave * 4 + r;                       // 16 segments x 8 rows = 128 rows
    pB[r] = Bt + (size_t)(n0 + q * 8 + l8) * K + (s8 ^ l8) * 8;
    lB[r] = &Bs[q * 512];
  }
  const int fr = lane & 15;
  const int c4 = lane >> 4;
  const int sk0 = (c4 ^ (fr & 7)) * 8;
  const int sk1 = ((4 | c4) ^ (fr & 7)) * 8;
  f32x4 acc[2][4] = {};
  for (int k0 = 0; k0 < K; k0 += 64) {
#pragma unroll
    for (int r = 0; r < 2; r++) gld_lds16(pA[r] + k0, lA[r]);
#pragma unroll
    for (int r = 0; r < 4; r++) gld_lds16(pB[r] + k0, lB[r]);
    asm volatile("s_waitcnt vmcnt(0)" ::: "memory");
    __syncthreads();
    {
      bf16x8 af0[2], bf0[4];
#pragma unroll
      for (int i = 0; i < 2; i++)
        af0[i] = *(const bf16x8*)&As[(wr + i * 16 + fr) * 64 + sk0];
#pragma unroll
      for (int j = 0; j < 4; j++)
        bf0[j] = *(const bf16x8*)&Bs[(wc + j * 16 + fr) * 64 + sk0];
#pragma unroll
      for (int i = 0; i < 2; i++)
#pragma unroll
        for (int j = 0; j < 4; j++)
          acc[i][j] = __builtin_amdgcn_mfma_f32_16x16x32_bf16(af0[i], bf0[j], acc[i][j], 0, 0, 0);
    }
    {
      bf16x8 af1[2], bf1[4];
#pragma unroll
      for (int i = 0; i < 2; i++)
        af1[i] = *(const bf16x8*)&As[(wr + i * 16 + fr) * 64 + sk1];
#pragma unroll
      for (int j = 0; j < 4; j++)
        bf1[j] = *(const bf16x8*)&Bs[(wc + j * 16 + fr) * 64 + sk1];
#pragma unroll
      for (int i = 0; i < 2; i++)
#pragma unroll
        for (int j = 0; j < 4; j++)
          acc[i][j] = __builtin_amdgcn_mfma_f32_16x16x32_bf16(af1[i], bf1[j], acc[i][j], 0, 0, 0);
    }
    __syncthreads();
  }
  const int crow = (lane >> 4) * 4;
  const int ccol = lane & 15;
#pragma unroll
  for (int i = 0; i < 2; i++) {
#pragma unroll
    for (int j = 0; j < 4; j++) {
      int n = n0 + wc + j * 16 + ccol;
      float c1 = t1[n];
      float c2 = t2[n];
#pragma unroll
      for (int r = 0; r < 4; r++) {
        int ml = wr + i * 16 + crow + r;
        float v = acc[i][j][r];
        v = srstd[ml] * (v - smu[ml] * c1) + c2;
        C[(size_t)(m0 + ml) * N + n] = v;
      }
    }
  }
}

// ---- K3: causal depthwise conv (k=4) + SiLU; bx==0 also computes dt softplus
__global__ void conv_silu_kernel(const unsigned short* __restrict__ zxbcdt,
                                 const float* __restrict__ conv_w,
                                 const float* __restrict__ conv_b,
                                 unsigned short* __restrict__ xbc_act,
                                 const float* __restrict__ dt_bias,
                                 float* __restrict__ dtb) {
  const int r0 = blockIdx.y * 8;
  if (blockIdx.x == 0) {
    for (int e = threadIdx.x; e < 8 * kNH; e += 192) {
      int rr = r0 + (e >> 5), h = e & 31;
      float x = bu2f(zxbcdt[(size_t)rr * kDProj + (kDProj - kNH) + h]) + dt_bias[h];
      dtb[(size_t)rr * kNH + h] = (x > 15.f) ? x : log1pf(expf(x));
    }
  }
  int c4 = blockIdx.x * 192 + threadIdx.x;
  if (c4 >= kConvDim / 4) return;
  const int c = c4 * 4;
  const int l0 = r0 & (kL - 1);
  float4 w[4];
  float bias[4];
#pragma unroll
  for (int q = 0; q < 4; q++) {
    w[q] = ((const float4*)conv_w)[c + q];
    bias[q] = conv_b[c + q];
  }
  float v[11][4];
#pragma unroll
  for (int i = 0; i < 11; i++) {
    int l = l0 - 3 + i;
    if (l >= 0) {
      ushort4 t = *(const ushort4*)&zxbcdt[(size_t)(r0 - 3 + i) * kDProj + kDI + c];
      v[i][0] = bu2f(t.x); v[i][1] = bu2f(t.y); v[i][2] = bu2f(t.z); v[i][3] = bu2f(t.w);
    } else {
      v[i][0] = v[i][1] = v[i][2] = v[i][3] = 0.f;
    }
  }
#pragma unroll
  for (int j = 0; j < 8; j++) {
    ushort4 o;
    unsigned short* op = (unsigned short*)&o;
#pragma unroll
    for (int q = 0; q < 4; q++) {
      float a = bias[q] + v[j][q] * w[q].x + v[j + 1][q] * w[q].y +
                v[j + 2][q] * w[q].z + v[j + 3][q] * w[q].w;
      op[q] = f2bu(a / (1.f + expf(-a)));
    }
    *(ushort4*)&xbc_act[(size_t)(r0 + j) * kConvDim + c] = o;
  }
}

// ---- K4: per-(b,chunk,head) end-of-chunk state via MFMA
__global__ __launch_bounds__(256) void chunk_state_kernel(
    const unsigned short* __restrict__ xbc_act,
    const float* __restrict__ dtbuf,
    const float* __restrict__ A_log,
    unsigned short* __restrict__ states,
    float* __restrict__ asum) {
  const int id = blockIdx.x;
  const int h = id & 31;
  const int c = (id >> 5) & (kNC - 1);
  const int b = id >> 11;
  const int tid = threadIdx.x;
  const int wave = tid >> 6, lane = tid & 63;
  __shared__ __align__(16) unsigned short sBT[kDS * kWS];
  __shared__ __align__(16) unsigned short sxd[kCS * kWS];
  __shared__ float s_dt[kCS];
  __shared__ float s_acum[kCS];
  const int l0 = b * kL + c * kCS;
  if (tid < kCS) s_dt[tid] = dtbuf[(size_t)(l0 + tid) * kNH + h];
  __syncthreads();
  if (tid < 64) {                      // wave-parallel inclusive scan
    float A = -expf(A_log[h]);
    float v = A * s_dt[tid];
#pragma unroll
    for (int off = 1; off < 64; off <<= 1) {
      float u = __shfl_up(v, off);
      if (tid >= off) v += u;
    }
    s_acum[tid] = v;
    if (tid == 63) asum[id] = v;
  }
  __syncthreads();
  const float total = s_acum[kCS - 1];
  for (int e = tid; e < kCS * kDS; e += 256) {
    int s = e >> 7, n = e & 127;
    sBT[n * kWS + s] = xbc_act[(size_t)(l0 + s) * kConvDim + kDI + n];
  }
  for (int e = tid; e < kCS * kHP; e += 256) {
    int s = e >> 6, p = e & 63;
    float xv = bu2f(xbc_act[(size_t)(l0 + s) * kConvDim + h * kHP + p]);
    sxd[p * kWS + s] = f2bu(xv * s_dt[s] * expf(total - s_acum[s]));
  }
  __syncthreads();
  const int arow = wave * 16 + (lane & 15);
  const int fk = (lane >> 4) * 8;
  f32x4 acc[8] = {};
#pragma unroll
  for (int kk = 0; kk < 2; kk++) {
    bf16x8 a = *(const bf16x8*)&sxd[arow * kWS + kk * 32 + fk];
#pragma unroll
    for (int j = 0; j < 8; j++) {
      bf16x8 bb = *(const bf16x8*)&sBT[(j * 16 + (lane & 15)) * kWS + kk * 32 + fk];
      acc[j] = __builtin_amdgcn_mfma_f32_16x16x32_bf16(a, bb, acc[j], 0, 0, 0);
    }
  }
  const int prow = wave * 16 + (lane >> 4) * 4;
  const int ncol = lane & 15;
  size_t base = (size_t)id * (kHP * kDS);
#pragma unroll
  for (int j = 0; j < 8; j++)
#pragma unroll
    for (int r = 0; r < 4; r++)
      states[base + (size_t)(prow + r) * kDS + j * 16 + ncol] = f2bu(acc[j][r]);
}

// ---- K5: sequential inter-chunk scan, ushort2 elements, depth-4 prefetch
__global__ void scan_kernel(unsigned short* __restrict__ states,
                            const float* __restrict__ asum) {
  const int blk = blockIdx.x;
  const int seg = blk & 15;
  const int bh = blk >> 4;
  const int h = bh & 31, b = bh >> 5;
  const int e2 = seg * 256 + threadIdx.x;               // ushort2 index, 4096/(b,h)
  const size_t cs = (size_t)kNH * 4096;                 // ushort2 units per chunk
  ushort2* p = (ushort2*)states + ((size_t)(b * kNC) * kNH + h) * 4096 + e2;
  const float* ap = asum + (b * kNC) * kNH + h;
  float c0 = 0.f, c1 = 0.f;
  ushort2 t0 = p[0];
  ushort2 t1v = p[cs];
  ushort2 t2v = p[2 * cs];
  ushort2 t3v = p[3 * cs];
  float d0 = expf(ap[0]);
  float d1 = expf(ap[kNH]);
  float d2 = expf(ap[2 * kNH]);
  float d3 = expf(ap[3 * kNH]);
  for (int g = 0; g < kNC; g += 4) {
    ushort2 n0 = t0, n1 = t1v, n2 = t2v, n3 = t3v;
    float e0 = d0, e1 = d1, e2f = d2, e3 = d3;
    if (g + 4 < kNC) {                                  // prefetch group g+4..g+7
      n0 = p[(size_t)(g + 4) * cs]; e0 = expf(ap[(g + 4) * kNH]);
      n1 = p[(size_t)(g + 5) * cs]; e1 = expf(ap[(g + 5) * kNH]);
      n2 = p[(size_t)(g + 6) * cs]; e2f = expf(ap[(g + 6) * kNH]);
      n3 = p[(size_t)(g + 7) * cs]; e3 = expf(ap[(g + 7) * kNH]);
    }
    ushort2 o;
    o.x = f2bu(c0); o.y = f2bu(c1); p[(size_t)g * cs] = o;
    c0 = c0 * d0 + bu2f(t0.x); c1 = c1 * d0 + bu2f(t0.y);
    o.x = f2bu(c0); o.y = f2bu(c1); p[(size_t)(g + 1) * cs] = o;
    c0 = c0 * d1 + bu2f(t1v.x); c1 = c1 * d1 + bu2f(t1v.y);
    o.x = f2bu(c0); o.y = f2bu(c1); p[(size_t)(g + 2) * cs] = o;
    c0 = c0 * d2 + bu2f(t2v.x); c1 = c1 * d2 + bu2f(t2v.y);
    o.x = f2bu(c0); o.y = f2bu(c1); p[(size_t)(g + 3) * cs] = o;
    c0 = c0 * d3 + bu2f(t3v.x); c1 = c1 * d3 + bu2f(t3v.y);
    t0 = n0; t1v = n1; t2v = n2; t3v = n3;
    d0 = e0; d1 = e1; d2 = e2f; d3 = e3;
  }
}

// ---- K6: intra-chunk Y, 4 heads/block (round-16 form, no register prefetch)
__global__ __launch_bounds__(256) void y_kernel(
    const unsigned short* __restrict__ xbc_act,
    const unsigned short* __restrict__ zxbcdt,
    const unsigned short* __restrict__ states_in,
    const float* __restrict__ dtbuf,
    const float* __restrict__ A_log,
    unsigned short* __restrict__ ybuf,
    float* __restrict__ pS, float* __restrict__ pQ) {
  const int id = blockIdx.x;                 // (b*NC + c)*8 + hg
  const int hg = id & 7;
  const int c = (id >> 3) & (kNC - 1);
  const int b = id >> 9;
  const int tid = threadIdx.x;
  const int wave = tid >> 6, lane = tid & 63;
  __shared__ __align__(16) unsigned short sC[kCS * kTS];
  __shared__ __align__(16) unsigned short sB[kCS * kTS];
  __shared__ __align__(16) unsigned short sxd[kCS * kWS];
  __shared__ __align__(16) unsigned short sW[kCS * kWS];
  __shared__ float s_dt[4][kCS];
  __shared__ float s_acum[4][kCS];
  const int l0 = b * kL + c * kCS;
  {
    int hh = tid >> 6, s = tid & 63;
    s_dt[hh][s] = dtbuf[(size_t)(l0 + s) * kNH + hg * 4 + hh];
  }
  __syncthreads();
  {                                          // wave-parallel scan, one head/wave
    int hh = tid >> 6, s = tid & 63;
    float A = -expf(A_log[hg * 4 + hh]);
    float v = A * s_dt[hh][s];
#pragma unroll
    for (int off = 1; off < 64; off <<= 1) {
      float u = __shfl_up(v, off);
      if (s >= off) v += u;
    }
    s_acum[hh][s] = v;
  }
  for (int e = tid; e < kCS * 16; e += 256) {
    int row = e >> 4, c8 = (e & 15) * 8;
    size_t rb = (size_t)(l0 + row) * kConvDim;
    *(ushort8*)&sB[row * kTS + c8] = *(const ushort8*)&xbc_act[rb + kDI + c8];
    *(ushort8*)&sC[row * kTS + c8] = *(const ushort8*)&xbc_act[rb + kDI + kDS + c8];
  }
  __syncthreads();
  const int arow = wave * 16 + (lane & 15);
  const int fk = (lane >> 4) * 8;
  // G[l][s] = C . B^T  (K=128) — head-independent, once per block
  f32x4 accG[4] = {};
#pragma unroll
  for (int kk = 0; kk < 4; kk++) {
    bf16x8 a = *(const bf16x8*)&sC[arow * kTS + kk * 32 + fk];
#pragma unroll
    for (int j = 0; j < 4; j++) {
      bf16x8 bb = *(const bf16x8*)&sB[(j * 16 + (lane & 15)) * kTS + kk * 32 + fk];
      accG[j] = __builtin_amdgcn_mfma_f32_16x16x32_bf16(a, bb, accG[j], 0, 0, 0);
    }
  }
  const int lrow = wave * 16 + (lane >> 4) * 4;
  const size_t sbase = (size_t)((b * kNC + c) * kNH) * (kHP * kDS);
  float rS[4] = {}, rQ[4] = {};
  for (int hh = 0; hh < 4; hh++) {
    const int h = hg * 4 + hh;
    __syncthreads();   // prior iteration (or G) done reading sB/sxd/sW
    // stage xd^T for this head
    for (int e = tid; e < kCS * kHP; e += 256) {
      int s = e >> 6, p = e & 63;
      float xv = bu2f(xbc_act[(size_t)(l0 + s) * kConvDim + h * kHP + p]);
      sxd[p * kWS + s] = f2bu(xv * s_dt[hh][s]);
    }
    // W = mask(G)*decay  (wave-local strip)
#pragma unroll
    for (int j = 0; j < 4; j++) {
      int scol = j * 16 + (lane & 15);
      float as = s_acum[hh][scol];
#pragma unroll
      for (int r = 0; r < 4; r++) {
        int l = lrow + r;
        float w = (scol <= l) ? accG[j][r] * expf(s_acum[hh][l] - as) : 0.f;
        sW[l * kWS + scol] = f2bu(w);
      }
    }
    // stage Sin[p][n] for this head into sB
    for (int e = tid; e < kCS * 16; e += 256) {
      int row = e >> 4, c8 = (e & 15) * 8;
      *(ushort8*)&sB[row * kTS + c8] =
          *(const ushort8*)&states_in[sbase + (size_t)h * (kHP * kDS) + row * kDS + c8];
    }
    __syncthreads();
    // Yd = W . xd^T  (K=64)
    f32x4 accY[4] = {};
#pragma unroll
    for (int kk = 0; kk < 2; kk++) {
      bf16x8 a = *(const bf16x8*)&sW[arow * kWS + kk * 32 + fk];
#pragma unroll
      for (int j = 0; j < 4; j++) {
        bf16x8 bb = *(const bf16x8*)&sxd[(j * 16 + (lane & 15)) * kWS + kk * 32 + fk];
        accY[j] = __builtin_amdgcn_mfma_f32_16x16x32_bf16(a, bb, accY[j], 0, 0, 0);
      }
    }
    // Yoff = C . Sin^T  (K=128)
    f32x4 accO[4] = {};
#pragma unroll
    for (int kk = 0; kk < 4; kk++) {
      bf16x8 a = *(const bf16x8*)&sC[arow * kTS + kk * 32 + fk];
#pragma unroll
      for (int j = 0; j < 4; j++) {
        bf16x8 bb = *(const bf16x8*)&sB[(j * 16 + (lane & 15)) * kTS + kk * 32 + fk];
        accO[j] = __builtin_amdgcn_mfma_f32_16x16x32_bf16(a, bb, accO[j], 0, 0, 0);
      }
    }
#pragma unroll
    for (int r = 0; r < 4; r++) {
      int l = lrow + r;
      float el = expf(s_acum[hh][l]);
      size_t zrow = (size_t)(l0 + l) * kDProj + h * kHP;
      size_t yrow = (size_t)(l0 + l) * kDI + h * kHP;
#pragma unroll
      for (int j = 0; j < 4; j++) {
        int p = j * 16 + (lane & 15);
        float yv = accY[j][r] + el * accO[j][r];
        float z = bu2f(zxbcdt[zrow + p]);
        yv *= z / (1.f + expf(-z));
        rS[r] += yv;
        rQ[r] += yv * yv;
        ybuf[yrow + p] = f2bu(yv);
      }
    }
  }
#pragma unroll
  for (int m = 1; m < 16; m <<= 1) {
#pragma unroll
    for (int r = 0; r < 4; r++) {
      rS[r] += __shfl_xor(rS[r], m);
      rQ[r] += __shfl_xor(rQ[r], m);
    }
  }
  if ((lane & 15) == 0) {
#pragma unroll
    for (int r = 0; r < 4; r++) {
      int row = l0 + lrow + r;
      pS[(size_t)row * 8 + hg] = rS[r];
      pQ[(size_t)row * 8 + hg] = rQ[r];
    }
  }
}

}  // namespace

extern "C" void kernel_launch(void* const* d_in, const int* in_sizes, int n_in,
                              void* d_out, int out_size, void* d_ws, size_t ws_size,
                              hipStream_t stream) {
  const float* u       = (const float*)d_in[0];
  const float* W_in    = (const float*)d_in[1];
  const float* conv_w  = (const float*)d_in[2];
  const float* conv_b  = (const float*)d_in[3];
  const float* dt_bias = (const float*)d_in[4];
  const float* A_log   = (const float*)d_in[5];
  const float* norm_w  = (const float*)d_in[6];
  const float* norm_b  = (const float*)d_in[7];
  const float* W_out   = (const float*)d_in[8];
  float* out = (float*)d_out;

  char* ws = (char*)d_ws;
  size_t off = 0;
  auto alloc = [&](size_t bytes) {
    void* p = ws + off;
    off += (bytes + 255) & ~(size_t)255;
    return p;
  };
  unsigned short* zxbcdt = (unsigned short*)alloc((size_t)kRows * kDProj * 2);        // 71.8 MB
  unsigned short* xbc    = (unsigned short*)alloc((size_t)kRows * kConvDim * 2);      // 37.7 MB
  float* dtb             = (float*)alloc((size_t)kRows * kNH * 4);                    //  1.0 MB
  float* asum            = (float*)alloc((size_t)kB * kNC * kNH * 4);                 // 16 KB
  unsigned short* A1     = (unsigned short*)alloc((size_t)kRows * 1024 * 2);          // 16.8 MB
  unsigned short* Bt1    = (unsigned short*)alloc((size_t)kDProjP * 1024 * 2);        //  9.2 MB
  unsigned short* states = (unsigned short*)alloc((size_t)kB * kNC * kNH * kHP * kDS * 2); // 67.1 MB
  unsigned short* Bt2    = (unsigned short*)alloc((size_t)1024 * kDI * 2);            //  4.2 MB
  unsigned short* ybuf   = (unsigned short*)alloc((size_t)kRows * kDI * 2);           // 33.6 MB
  float* t1              = (float*)alloc(1024 * 4);
  float* t2              = (float*)alloc(1024 * 4);
  float* pS              = (float*)alloc((size_t)kRows * 8 * 4);                      // 256 KB
  float* pQ              = (float*)alloc((size_t)kRows * 8 * 4);                      // 256 KB
  (void)ws_size; (void)in_sizes; (void)n_in; (void)out_size;

  constexpr int kPrepBlocks = kRows * 1024 / 4 / 256                    // 8192
                            + (kDProjP / 32) * (1024 / 32)              // 4480
                            + (1024 / 32) * (2048 / 32)                 // 2048
                            + 16;                                       // 14736
  prep_kernel<<<kPrepBlocks, 256, 0, stream>>>(
      (const float4*)u, (ushort4*)A1, W_in, Bt1, W_out, Bt2, norm_w, norm_b, t1, t2);
  gemm_in<<<dim3(kDProjP / 128, kRows / 128), 256, 0, stream>>>(
      A1, Bt1, zxbcdt, kRows, kDProj, 1024);
  conv_silu_kernel<<<dim3(3, kRows / 8), 192, 0, stream>>>(zxbcdt, conv_w, conv_b, xbc,
                                                           dt_bias, dtb);
  chunk_state_kernel<<<kB * kNC * kNH, 256, 0, stream>>>(xbc, dtb, A_log, states, asum);
  scan_kernel<<<kB * kNH * 16, 256, 0, stream>>>(states, asum);
  y_kernel<<<kB * kNC * 8, 256, 0, stream>>>(xbc, zxbcdt, states, dtb, A_log, ybuf, pS, pQ);
  gemm_fold<<<dim3(1024 / 128, kRows / 64), 256, 0, stream>>>(
      ybuf, Bt2, out, kRows, 1024, 2048, pS, pQ, t1, t2);
}